// Round 1
// baseline (3448.690 us; speedup 1.0000x reference)
//
#include <hip/hip_runtime.h>
#include <hip/hip_fp16.h>
#include <cstdint>
#include <cstddef>

#define NN 1024   // nodes
#define BB 32     // batch
#define FD 66     // features per node (2 + 64)
#define FB 2112   // FD*BB

// ---------------------------------------------------------------------------
// K1: build x0.  Layout: X0[n*FB + b*FD + f] = x[b,n,f]
//     (reference uses c=f*B+b; any consistent column permutation is exact
//      since the supports GEMM is column-independent)
// ---------------------------------------------------------------------------
__global__ __launch_bounds__(256) void k_build_x0(
    const float* __restrict__ inp, const float* __restrict__ state,
    float* __restrict__ X0) {
  int idx = blockIdx.x * 256 + threadIdx.x;
  if (idx >= NN * FB) return;
  int n = idx / FB;
  int r = idx - n * FB;
  int b = r / FD;
  int f = r - b * FD;
  float v = (f < 2) ? inp[b * (NN * 2) + n * 2 + f]
                    : state[(size_t)b * (NN * 64) + n * 64 + (f - 2)];
  X0[idx] = v;
}

// ---------------------------------------------------------------------------
// K2: supports GEMM.  xk[m][i][c] = sum_j mats[m][i][j] * x0[j][c]
// mats: m=0: a0; m=1..4: mask[0..3]*a0; m=5..8: mask[4..7]*a1; m=9: a1
// Coefficients computed on the fly from adj/mask.  Output fp16.
// Block: 256 thr, tile 32 i x 64 c, all 10 m.  Thread: 2i x 4c x 10m accums.
// ---------------------------------------------------------------------------
__global__ __launch_bounds__(256) void k_supports(
    const float* __restrict__ adj, const float* __restrict__ mask,
    const float* __restrict__ X0, __half* __restrict__ XK) {
  __shared__ float coefL[16][10][32];  // [jj][l][i]  l: 0=a0 1=a1 2..9=mask0..7
  __shared__ float x0s[16][64];
  const int tid = threadIdx.x;
  const int c0 = blockIdx.x * 64;
  const int i0 = blockIdx.y * 32;
  const int cg = tid & 15;   // c group: c = c0 + cg*4 + {0..3}
  const int ig = tid >> 4;   // i group: i = i0 + ig*2 + {0,1}

  float acc[10][2][4];
#pragma unroll
  for (int m = 0; m < 10; ++m)
#pragma unroll
    for (int i = 0; i < 2; ++i)
#pragma unroll
      for (int c = 0; c < 4; ++c) acc[m][i][c] = 0.f;

  for (int j0 = 0; j0 < NN; j0 += 16) {
    __syncthreads();
    // stage coefficients: 10 arrays x 32 i x 16 j
#pragma unroll
    for (int p = 0; p < 20; ++p) {
      int flat = p * 256 + tid;          // 0..5119
      int l = flat >> 9;                 // /512 -> 0..9
      int rem = flat & 511;
      int il = rem >> 4;                 // 0..31
      int jl = rem & 15;                 // 0..15
      const float* sp = (l == 0) ? adj
                      : (l == 1) ? (adj + (size_t)NN * NN)
                                 : (mask + (size_t)(l - 2) * NN * NN);
      coefL[jl][l][il] = sp[(size_t)(i0 + il) * NN + (j0 + jl)];
    }
    // stage x0: 16 j x 64 c
#pragma unroll
    for (int p = 0; p < 4; ++p) {
      int flat = p * 256 + tid;
      int jl = flat >> 6;
      int cl = flat & 63;
      x0s[jl][cl] = X0[(size_t)(j0 + jl) * FB + c0 + cl];
    }
    __syncthreads();
#pragma unroll 4
    for (int jj = 0; jj < 16; ++jj) {
      float4 xv = *reinterpret_cast<const float4*>(&x0s[jj][cg * 4]);
      float xa[4] = {xv.x, xv.y, xv.z, xv.w};
      float2 cf[10];
#pragma unroll
      for (int l = 0; l < 10; ++l)
        cf[l] = *reinterpret_cast<const float2*>(&coefL[jj][l][ig * 2]);
#pragma unroll
      for (int i = 0; i < 2; ++i) {
        float a0v = i ? cf[0].y : cf[0].x;
        float a1v = i ? cf[1].y : cf[1].x;
        float m0 = i ? cf[2].y : cf[2].x;
        float m1 = i ? cf[3].y : cf[3].x;
        float m2 = i ? cf[4].y : cf[4].x;
        float m3 = i ? cf[5].y : cf[5].x;
        float m4 = i ? cf[6].y : cf[6].x;
        float m5 = i ? cf[7].y : cf[7].x;
        float m6 = i ? cf[8].y : cf[8].x;
        float m7 = i ? cf[9].y : cf[9].x;
#pragma unroll
        for (int c = 0; c < 4; ++c) {
          float p0 = a0v * xa[c];
          float p1 = a1v * xa[c];
          acc[0][i][c] += p0;
          acc[1][i][c] += m0 * p0;
          acc[2][i][c] += m1 * p0;
          acc[3][i][c] += m2 * p0;
          acc[4][i][c] += m3 * p0;
          acc[5][i][c] += m4 * p1;
          acc[6][i][c] += m5 * p1;
          acc[7][i][c] += m6 * p1;
          acc[8][i][c] += m7 * p1;
          acc[9][i][c] += p1;
        }
      }
    }
  }
#pragma unroll
  for (int m = 0; m < 10; ++m)
#pragma unroll
    for (int i = 0; i < 2; ++i) {
      int row = i0 + ig * 2 + i;
      __half2* dst = reinterpret_cast<__half2*>(
          &XK[((size_t)m * NN + row) * FB + c0 + cg * 4]);
      dst[0] = __floats2half2_rn(acc[m][i][0], acc[m][i][1]);
      dst[1] = __floats2half2_rn(acc[m][i][2], acc[m][i][3]);
    }
}

// ---------------------------------------------------------------------------
// K3: projection.  XP[s][n][b][o] = sum_f src_s[n][b*FD+f] * W[f][o]
// s=0: src = X0 (fp32), s=1..10: src = XK[s-1] (fp16).  Output fp16.
// Block = (n, s).  srcT[f][b] + W staged in LDS.
// ---------------------------------------------------------------------------
template <int O>
__global__ __launch_bounds__(256) void k_proj(
    const float* __restrict__ X0, const __half* __restrict__ XK,
    const float* __restrict__ W, __half* __restrict__ XP) {
  const int n = blockIdx.x;
  const int s = blockIdx.y;  // 0..10
  __shared__ float srcT[FD * 36];  // [f][b], padded stride 36
  __shared__ float wL[FD * O];
  const int tid = threadIdx.x;
  for (int p = tid; p < FB; p += 256) {
    int b = p / FD;
    int f = p - b * FD;
    float v = (s == 0) ? X0[(size_t)n * FB + p]
                       : __half2float(XK[((size_t)(s - 1) * NN + n) * FB + p]);
    srcT[f * 36 + b] = v;
  }
  for (int p = tid; p < FD * O; p += 256) wL[p] = W[p];
  __syncthreads();
  constexpr int OG = O / 4;        // o groups
  constexpr int BG = 256 / OG;     // b groups
  constexpr int BPT = 32 / BG;     // b per thread (4 for O=128, 2 for O=64)
  const int og = tid % OG;
  const int bg = tid / OG;
  const int o0 = og * 4;
  const int b0 = bg * BPT;
  float acc[BPT][4];
#pragma unroll
  for (int i = 0; i < BPT; ++i)
#pragma unroll
    for (int j = 0; j < 4; ++j) acc[i][j] = 0.f;
  for (int f = 0; f < FD; ++f) {
    float4 wv = *reinterpret_cast<const float4*>(&wL[f * O + o0]);
    float wa[4] = {wv.x, wv.y, wv.z, wv.w};
#pragma unroll
    for (int bb = 0; bb < BPT; ++bb) {
      float sv = srcT[f * 36 + b0 + bb];
#pragma unroll
      for (int oo = 0; oo < 4; ++oo) acc[bb][oo] += sv * wa[oo];
    }
  }
#pragma unroll
  for (int bb = 0; bb < BPT; ++bb) {
    __half2* dst = reinterpret_cast<__half2*>(
        &XP[(((size_t)s * NN + n) * BB + b0 + bb) * O + o0]);
    dst[0] = __floats2half2_rn(acc[bb][0], acc[bb][1]);
    dst[1] = __floats2half2_rn(acc[bb][2], acc[bb][3]);
  }
}

// ---------------------------------------------------------------------------
// K4: attention.  Per node n: for the 10 supports (srcs 1..10 of XP),
// h = relu(xp @ Watt[n]); s = h @ Watt1[n]; softmax over k=5 per group;
// XI/XS[b][n][o] = sum_k a[k] * xp[k][o].
// Block per n; loop over 4 b-quads (8 b each); rows r = si*8 + bq (80 rows).
// ---------------------------------------------------------------------------
template <int O>
__global__ __launch_bounds__(256) void k_attend(
    const __half* __restrict__ XP, const float* __restrict__ Watt,
    const float* __restrict__ Watt1, float* __restrict__ XI,
    float* __restrict__ XS) {
  constexpr int QG = O / 4;     // q groups
  constexpr int RG = 256 / QG;  // row groups
  constexpr int RP = RG * 4;    // rows per pass
  const int n = blockIdx.x;
  const int tid = threadIdx.x;
  __shared__ __half wattL[O * O];
  __shared__ float watt1L[O];
  __shared__ __half xpL[80 * O];
  __shared__ float sPart[RP * (QG + 1)];
  __shared__ float sL[80];
  __shared__ float aL[16][5];

  {
    const float2* wsrc =
        reinterpret_cast<const float2*>(Watt + (size_t)n * O * O);
    __half2* wdst = reinterpret_cast<__half2*>(wattL);
    for (int p = tid; p < O * O / 2; p += 256) {
      float2 wv = wsrc[p];
      wdst[p] = __floats2half2_rn(wv.x, wv.y);
    }
    for (int p = tid; p < O; p += 256) watt1L[p] = Watt1[(size_t)n * O + p];
  }

  const int qg = tid % QG;
  const int rg = tid / QG;
  const int q0 = qg * 4;

  for (int quad = 0; quad < 4; ++quad) {
    __syncthreads();  // protects xpL from previous quad's readers
    {
      const uint32_t* xsrc = reinterpret_cast<const uint32_t*>(XP);
      uint32_t* xdst = reinterpret_cast<uint32_t*>(xpL);
      for (int p = tid; p < 80 * (O / 2); p += 256) {
        int r = p / (O / 2);
        int oh = p - r * (O / 2);
        int si = r >> 3;
        int bq = r & 7;
        size_t gi =
            (((size_t)(1 + si) * NN + n) * BB + quad * 8 + bq) * (O / 2) + oh;
        xdst[p] = xsrc[gi];
      }
    }
    __syncthreads();

    for (int pass = 0; pass * RP < 80; ++pass) {
      const int r0 = pass * RP + rg * 4;
      if (r0 < 80) {
        float h[4][4];
#pragma unroll
        for (int a = 0; a < 4; ++a)
#pragma unroll
          for (int b = 0; b < 4; ++b) h[a][b] = 0.f;
#pragma unroll 8
        for (int o = 0; o < O; o += 2) {
          const __half2* w0p =
              reinterpret_cast<const __half2*>(&wattL[o * O + q0]);
          const __half2* w1p =
              reinterpret_cast<const __half2*>(&wattL[(o + 1) * O + q0]);
          float2 wa = __half22float2(w0p[0]);
          float2 wb = __half22float2(w0p[1]);
          float2 wc = __half22float2(w1p[0]);
          float2 wd = __half22float2(w1p[1]);
          float w0[4] = {wa.x, wa.y, wb.x, wb.y};
          float w1[4] = {wc.x, wc.y, wd.x, wd.y};
#pragma unroll
          for (int rr = 0; rr < 4; ++rr) {
            float2 xf = __half22float2(
                *reinterpret_cast<const __half2*>(&xpL[(r0 + rr) * O + o]));
#pragma unroll
            for (int qq = 0; qq < 4; ++qq)
              h[rr][qq] += xf.x * w0[qq] + xf.y * w1[qq];
          }
        }
#pragma unroll
        for (int rr = 0; rr < 4; ++rr) {
          float pv = 0.f;
#pragma unroll
          for (int qq = 0; qq < 4; ++qq)
            pv += fmaxf(h[rr][qq], 0.f) * watt1L[q0 + qq];
          sPart[(rg * 4 + rr) * (QG + 1) + qg] = pv;
        }
      }
      __syncthreads();
      int nval = 80 - pass * RP;
      if (nval > RP) nval = RP;
      for (int r = tid; r < nval; r += 256) {
        float ssum = 0.f;
        for (int g = 0; g < QG; ++g) ssum += sPart[r * (QG + 1) + g];
        sL[pass * RP + r] = ssum;
      }
      __syncthreads();
    }

    if (tid < 16) {
      const int g = tid >> 3;
      const int bq = tid & 7;
      float sv[5];
#pragma unroll
      for (int k = 0; k < 5; ++k) sv[k] = sL[(g * 5 + k) * 8 + bq];
      float mx = sv[0];
#pragma unroll
      for (int k = 1; k < 5; ++k) mx = fmaxf(mx, sv[k]);
      float e[5], sum = 0.f;
#pragma unroll
      for (int k = 0; k < 5; ++k) {
        e[k] = expf(sv[k] - mx);
        sum += e[k];
      }
      float inv = 1.f / sum;
#pragma unroll
      for (int k = 0; k < 5; ++k) aL[tid][k] = e[k] * inv;
    }
    __syncthreads();

    constexpr int OGW = O / 4;
    const int o0w = (tid % OGW) * 4;
    for (int pr = tid / OGW; pr < 16; pr += 256 / OGW) {
      const int g = pr >> 3;
      const int bq = pr & 7;
      float o4[4] = {0.f, 0.f, 0.f, 0.f};
#pragma unroll
      for (int k = 0; k < 5; ++k) {
        float av = aL[pr][k];
        const __half2* xr = reinterpret_cast<const __half2*>(
            &xpL[((g * 5 + k) * 8 + bq) * O + o0w]);
        float2 x01 = __half22float2(xr[0]);
        float2 x23 = __half22float2(xr[1]);
        o4[0] += av * x01.x;
        o4[1] += av * x01.y;
        o4[2] += av * x23.x;
        o4[3] += av * x23.y;
      }
      float* dst =
          (g ? XS : XI) + ((size_t)(quad * 8 + bq) * NN + n) * O + o0w;
      *reinterpret_cast<float4*>(dst) = make_float4(o4[0], o4[1], o4[2], o4[3]);
    }
  }
}

// ---------------------------------------------------------------------------
// K5: ru output: g = [xi|xs|xbp] @ Wout + b ; value = sigmoid(g);
//     o<64 -> RHX = value*hx ; o>=64 -> UBUF = value
// ---------------------------------------------------------------------------
__global__ __launch_bounds__(256) void k_wout_ru(
    const float* __restrict__ XI, const float* __restrict__ XS,
    const __half* __restrict__ XP, const float* __restrict__ Wout,
    const float* __restrict__ bias, const float* __restrict__ hx,
    float* __restrict__ RHX, float* __restrict__ UBUF) {
  const int n = blockIdx.x;
  const int tid = threadIdx.x;
  __shared__ float catT[384 * 36];
  for (int p = tid; p < 384 * 32; p += 256) {
    int b = p / 384;
    int op = p - b * 384;
    float v;
    if (op < 128)
      v = XI[((size_t)b * NN + n) * 128 + op];
    else if (op < 256)
      v = XS[((size_t)b * NN + n) * 128 + (op - 128)];
    else
      v = __half2float(XP[((size_t)n * BB + b) * 128 + (op - 256)]);  // s=0
    catT[op * 36 + b] = v;
  }
  __syncthreads();
  const int og = tid & 31;
  const int bg = tid >> 5;
  const int o0 = og * 4;
  const int b0 = bg * 4;
  float acc[4][4];
#pragma unroll
  for (int i = 0; i < 4; ++i)
#pragma unroll
    for (int j = 0; j < 4; ++j) acc[i][j] = 0.f;
#pragma unroll 4
  for (int op = 0; op < 384; ++op) {
    float4 cv = *reinterpret_cast<const float4*>(&catT[op * 36 + b0]);
    float4 wv = *reinterpret_cast<const float4*>(&Wout[(size_t)op * 128 + o0]);
    float ca[4] = {cv.x, cv.y, cv.z, cv.w};
    float wa[4] = {wv.x, wv.y, wv.z, wv.w};
#pragma unroll
    for (int bb = 0; bb < 4; ++bb)
#pragma unroll
      for (int oo = 0; oo < 4; ++oo) acc[bb][oo] += ca[bb] * wa[oo];
  }
#pragma unroll
  for (int bb = 0; bb < 4; ++bb) {
    int b = b0 + bb;
    size_t base = (size_t)b * (NN * 64) + n * 64;
#pragma unroll
    for (int oo = 0; oo < 4; ++oo) {
      int o = o0 + oo;
      float val = acc[bb][oo] + bias[o];
      val = 1.f / (1.f + expf(-val));
      if (o < 64)
        RHX[base + o] = val * hx[base + o];
      else
        UBUF[base + (o - 64)] = val;
    }
  }
}

// ---------------------------------------------------------------------------
// K6: candidate output + final gate: c = tanh([xi|xs|xbp] @ Wout_c + b_c);
//     out = u*hx + (1-u)*c
// ---------------------------------------------------------------------------
__global__ __launch_bounds__(256) void k_wout_c(
    const float* __restrict__ XI, const float* __restrict__ XS,
    const __half* __restrict__ XP, const float* __restrict__ Wout,
    const float* __restrict__ bias, const float* __restrict__ UBUF,
    const float* __restrict__ hx, float* __restrict__ out) {
  const int n = blockIdx.x;
  const int tid = threadIdx.x;
  __shared__ float catT[192 * 36];
  for (int p = tid; p < 192 * 32; p += 256) {
    int b = p / 192;
    int op = p - b * 192;
    float v;
    if (op < 64)
      v = XI[((size_t)b * NN + n) * 64 + op];
    else if (op < 128)
      v = XS[((size_t)b * NN + n) * 64 + (op - 64)];
    else
      v = __half2float(XP[((size_t)n * BB + b) * 64 + (op - 128)]);  // s=0
    catT[op * 36 + b] = v;
  }
  __syncthreads();
  const int og = tid & 15;
  const int bg = tid >> 4;
  const int o0 = og * 4;
  const int b0 = bg * 2;
  float acc[2][4];
#pragma unroll
  for (int i = 0; i < 2; ++i)
#pragma unroll
    for (int j = 0; j < 4; ++j) acc[i][j] = 0.f;
#pragma unroll 4
  for (int op = 0; op < 192; ++op) {
    float2 cv = *reinterpret_cast<const float2*>(&catT[op * 36 + b0]);
    float4 wv = *reinterpret_cast<const float4*>(&Wout[(size_t)op * 64 + o0]);
    float wa[4] = {wv.x, wv.y, wv.z, wv.w};
#pragma unroll
    for (int oo = 0; oo < 4; ++oo) {
      acc[0][oo] += cv.x * wa[oo];
      acc[1][oo] += cv.y * wa[oo];
    }
  }
#pragma unroll
  for (int bb = 0; bb < 2; ++bb) {
    int b = b0 + bb;
#pragma unroll
    for (int oo = 0; oo < 4; ++oo) {
      int o = o0 + oo;
      float cval = tanhf(acc[bb][oo] + bias[o]);
      size_t idx = (size_t)b * (NN * 64) + n * 64 + o;
      float u = UBUF[idx];
      out[idx] = u * hx[idx] + (1.f - u) * cval;
    }
  }
}

// ---------------------------------------------------------------------------
extern "C" void kernel_launch(void* const* d_in, const int* in_sizes, int n_in,
                              void* d_out, int out_size, void* d_ws,
                              size_t ws_size, hipStream_t stream) {
  const float* inputs   = (const float*)d_in[0];
  const float* hx       = (const float*)d_in[1];
  const float* adj      = (const float*)d_in[2];
  const float* mask     = (const float*)d_in[3];
  const float* W_ru     = (const float*)d_in[4];
  const float* Watt_ru  = (const float*)d_in[5];
  const float* Watt1_ru = (const float*)d_in[6];
  const float* Wout_ru  = (const float*)d_in[7];
  const float* b_ru     = (const float*)d_in[8];
  const float* W_c      = (const float*)d_in[9];
  const float* Watt_c   = (const float*)d_in[10];
  const float* Watt1_c  = (const float*)d_in[11];
  const float* Wout_c   = (const float*)d_in[12];
  const float* b_c      = (const float*)d_in[13];

  // workspace arena (needs ~161 MB):
  //   X0   fp32 [1024][2112]            @ 0         (8,650,752 B)
  //   XK   fp16 [10][1024][2112]        @ 8,650,752 (43,253,760 B)
  //     XI fp32 [32][1024][128] aliases XK (dead after k_proj)
  //     XS fp32 [32][1024][128] aliases XK+16,777,216
  //   XP   fp16 [11][1024][32][128]     @ 51,904,512 (92,274,688 B)
  //   RHX  fp32 [32][65536]             @ 144,179,200
  //   UBUF fp32 [32][65536]             @ 152,567,808   (end 160,956,416)
  char* ws = (char*)d_ws;
  float*  X0   = (float*)(ws);
  __half* XK   = (__half*)(ws + 8650752);
  float*  XI   = (float*)(ws + 8650752);
  float*  XS   = (float*)(ws + 8650752 + 16777216);
  __half* XP   = (__half*)(ws + 51904512);
  float*  RHX  = (float*)(ws + 144179200);
  float*  UBUF = (float*)(ws + 152567808);
  float*  out  = (float*)d_out;

  // ---- gate gconv (O = 2U = 128) ----
  k_build_x0<<<8448, 256, 0, stream>>>(inputs, hx, X0);
  k_supports<<<dim3(33, 32), 256, 0, stream>>>(adj, mask, X0, XK);
  k_proj<128><<<dim3(1024, 11), 256, 0, stream>>>(X0, XK, W_ru, XP);
  k_attend<128><<<1024, 256, 0, stream>>>(XP, Watt_ru, Watt1_ru, XI, XS);
  k_wout_ru<<<1024, 256, 0, stream>>>(XI, XS, XP, Wout_ru, b_ru, hx, RHX, UBUF);
  // ---- candidate gconv (O = U = 64), state = r*hx ----
  k_build_x0<<<8448, 256, 0, stream>>>(inputs, RHX, X0);
  k_supports<<<dim3(33, 32), 256, 0, stream>>>(adj, mask, X0, XK);
  k_proj<64><<<dim3(1024, 11), 256, 0, stream>>>(X0, XK, W_c, XP);
  k_attend<64><<<1024, 256, 0, stream>>>(XP, Watt_c, Watt1_c, XI, XS);
  k_wout_c<<<1024, 256, 0, stream>>>(XI, XS, XP, Wout_c, b_c, UBUF, hx, out);
}

// Round 2
// 869.187 us; speedup vs baseline: 3.9677x; 3.9677x over previous
//
#include <hip/hip_runtime.h>
#include <hip/hip_fp16.h>
#include <cstdint>
#include <cstddef>

#define NN 1024   // nodes
#define BB 32     // batch
#define FD 66     // features per node (2 + 64)
#define FB 2112   // FD*BB

typedef _Float16 f16x8 __attribute__((ext_vector_type(8)));
typedef _Float16 f16x4 __attribute__((ext_vector_type(4)));
typedef float f32x4 __attribute__((ext_vector_type(4)));

__device__ __forceinline__ void load_lds16(const void* g, void* l) {
  __builtin_amdgcn_global_load_lds(
      (const __attribute__((address_space(1))) void*)g,
      (__attribute__((address_space(3))) void*)l, 16, 0, 0);
}

// ---------------------------------------------------------------------------
// K0: build the 10 support matrices (shared by both gconvs), fp16.
// A_all[(m*1024+i)*1024+j]: m=0:a0, 1..4:mask[0..3]*a0, 5..8:mask[4..7]*a1, 9:a1
// ---------------------------------------------------------------------------
__global__ __launch_bounds__(256) void k_build_amats(
    const float* __restrict__ adj, const float* __restrict__ mask,
    _Float16* __restrict__ A) {
  int q = blockIdx.x * 256 + threadIdx.x;  // 0..262143 quads
  int i = q >> 8;
  int j0 = (q & 255) << 2;
  size_t off = (size_t)i * 1024 + j0;
  float4 a0 = *(const float4*)(adj + off);
  float4 a1 = *(const float4*)(adj + (1u << 20) + off);
  f16x4 r;
  r[0] = a0.x; r[1] = a0.y; r[2] = a0.z; r[3] = a0.w;
  *(f16x4*)(A + off) = r;
  r[0] = a1.x; r[1] = a1.y; r[2] = a1.z; r[3] = a1.w;
  *(f16x4*)(A + (size_t)9 * 1048576 + off) = r;
#pragma unroll
  for (int l = 0; l < 8; ++l) {
    float4 mk = *(const float4*)(mask + (size_t)l * 1048576 + off);
    float4 base = (l < 4) ? a0 : a1;
    r[0] = mk.x * base.x; r[1] = mk.y * base.y;
    r[2] = mk.z * base.z; r[3] = mk.w * base.w;
    *(f16x4*)(A + (size_t)(l + 1) * 1048576 + off) = r;
  }
}

// ---------------------------------------------------------------------------
// K1: build x0 fp32.  X0[n*FB + b*FD + f] = x[b,n,f]  (for proj s=0)
// ---------------------------------------------------------------------------
__global__ __launch_bounds__(256) void k_build_x0(
    const float* __restrict__ inp, const float* __restrict__ state,
    float* __restrict__ X0) {
  int idx = blockIdx.x * 256 + threadIdx.x;
  if (idx >= NN * FB) return;
  int n = idx / FB;
  int r = idx - n * FB;
  int b = r / FD;
  int f = r - b * FD;
  float v = (f < 2) ? inp[b * (NN * 2) + n * 2 + f]
                    : state[(size_t)b * (NN * 64) + n * 64 + (f - 2)];
  X0[idx] = v;
}

// ---------------------------------------------------------------------------
// K1b: build X0^T fp16, padded to 2176 rows.  X0T[(b*66+f)*1024 + n]
// ---------------------------------------------------------------------------
__global__ __launch_bounds__(256) void k_build_x0t(
    const float* __restrict__ inp, const float* __restrict__ state,
    _Float16* __restrict__ X0T) {
  __shared__ float tile[64 * 65];
  const int b = blockIdx.x;        // 0..31
  const int n0 = blockIdx.y * 64;  // 0..960
  const int tid = threadIdx.x;
  for (int p = tid; p < 4096; p += 256) {
    int nn = p >> 6, f = p & 63;
    tile[f * 65 + nn] = state[(size_t)b * 65536 + (n0 + nn) * 64 + f];
  }
  __syncthreads();
  for (int p = tid; p < 4096; p += 256) {
    int f = p >> 6, nn = p & 63;
    X0T[(size_t)(b * 66 + 2 + f) * 1024 + n0 + nn] = (_Float16)tile[f * 65 + nn];
  }
  if (tid < 128) {
    int f = tid >> 6, nn = tid & 63;
    X0T[(size_t)(b * 66 + f) * 1024 + n0 + nn] =
        (_Float16)inp[(size_t)b * 2048 + (n0 + nn) * 2 + f];
  }
}

// ---------------------------------------------------------------------------
// K2: supports GEMM via MFMA.  C[10240][2112] = A_all[10240][1024] @ X0
//     (B-operand read from X0T[c][j]).  C stored fp16 into XK.
// 128x128 tile, BK=32, 4 waves (2x2), each wave 64x64 via 4x4 16x16x32 frags.
// LDS staged with global_load_lds w16; slot^(row&3) swizzle pre-applied on the
// global source (rule #21) so ds_read_b128 is <=2-way bank conflicted.
// ---------------------------------------------------------------------------
__global__ __launch_bounds__(256, 2) void k_supports_mfma(
    const _Float16* __restrict__ A, const _Float16* __restrict__ BT,
    __half* __restrict__ XK) {
  __shared__ _Float16 ldsA[2][4096];  // [buf][128 rows][32 k]
  __shared__ _Float16 ldsB[2][4096];
  const int tid = threadIdx.x;
  const int bn = blockIdx.x;  // 0..16 (col tiles, last partial)
  const int bm = blockIdx.y;  // 0..79
  const int l = tid & 63;
  const int w = tid >> 6;
  const int wr = w >> 1, wc = w & 1;

  // staging: thread covers chunks t0=tid, t1=256+tid; 16B each
  const int t0 = tid, t1 = 256 + tid;
  const int r0 = t0 >> 2, q0 = (t0 & 3) ^ (r0 & 3);
  const int r1 = t1 >> 2, q1 = (t1 & 3) ^ (r1 & 3);
  const _Float16* gA0 = A + ((size_t)(bm * 128 + r0)) * 1024 + q0 * 8;
  const _Float16* gA1 = A + ((size_t)(bm * 128 + r1)) * 1024 + q1 * 8;
  const _Float16* gB0 = BT + ((size_t)(bn * 128 + r0)) * 1024 + q0 * 8;
  const _Float16* gB1 = BT + ((size_t)(bn * 128 + r1)) * 1024 + q1 * 8;

  // ds_read fragment offsets (halfs), swizzled
  const int ps = ((l >> 4) ^ (l & 3)) * 8;  // physical slot * 8
  int offA[4], offB[4];
#pragma unroll
  for (int i = 0; i < 4; ++i) {
    offA[i] = (wr * 64 + i * 16 + (l & 15)) * 32 + ps;
    offB[i] = (wc * 64 + i * 16 + (l & 15)) * 32 + ps;
  }

  f32x4 acc[4][4];
#pragma unroll
  for (int i = 0; i < 4; ++i)
#pragma unroll
    for (int j = 0; j < 4; ++j) acc[i][j] = (f32x4){0.f, 0.f, 0.f, 0.f};

  // prologue stage
  load_lds16(gA0, &ldsA[0][0] + t0 * 8);
  load_lds16(gA1, &ldsA[0][0] + t1 * 8);
  load_lds16(gB0, &ldsB[0][0] + t0 * 8);
  load_lds16(gB1, &ldsB[0][0] + t1 * 8);

  int buf = 0;
  for (int kt = 0; kt < 32; ++kt) {
    __syncthreads();  // stage(buf) visible; prev readers of buf^1 done
    if (kt + 1 < 32) {
      int k0 = (kt + 1) * 32;
      load_lds16(gA0 + k0, &ldsA[buf ^ 1][0] + t0 * 8);
      load_lds16(gA1 + k0, &ldsA[buf ^ 1][0] + t1 * 8);
      load_lds16(gB0 + k0, &ldsB[buf ^ 1][0] + t0 * 8);
      load_lds16(gB1 + k0, &ldsB[buf ^ 1][0] + t1 * 8);
    }
    f16x8 af[4], bf[4];
#pragma unroll
    for (int i = 0; i < 4; ++i)
      af[i] = *(const f16x8*)(&ldsA[buf][offA[i]]);
#pragma unroll
    for (int i = 0; i < 4; ++i)
      bf[i] = *(const f16x8*)(&ldsB[buf][offB[i]]);
#pragma unroll
    for (int i = 0; i < 4; ++i)
#pragma unroll
      for (int j = 0; j < 4; ++j)
        acc[i][j] = __builtin_amdgcn_mfma_f32_16x16x32_f16(af[i], bf[j],
                                                           acc[i][j], 0, 0, 0);
    buf ^= 1;
  }

  // epilogue: C/D layout col=lane&15, row=(lane>>4)*4+reg
#pragma unroll
  for (int i = 0; i < 4; ++i) {
    int R = bm * 128 + wr * 64 + i * 16 + (l >> 4) * 4;
#pragma unroll
    for (int j = 0; j < 4; ++j) {
      int colb = bn * 128 + wc * 64 + j * 16;
      if (colb >= FB) continue;  // uniform guard for last col tile
      int col = colb + (l & 15);
#pragma unroll
      for (int r = 0; r < 4; ++r)
        XK[(size_t)(R + r) * FB + col] = __float2half(acc[i][j][r]);
    }
  }
}

// ---------------------------------------------------------------------------
// K3: projection.  XP[s][n][b][o] = sum_f src_s[n][b*FD+f] * W[f][o]
// ---------------------------------------------------------------------------
template <int O>
__global__ __launch_bounds__(256) void k_proj(
    const float* __restrict__ X0, const __half* __restrict__ XK,
    const float* __restrict__ W, __half* __restrict__ XP) {
  const int n = blockIdx.x;
  const int s = blockIdx.y;  // 0..10
  __shared__ float srcT[FD * 36];  // [f][b], padded stride 36
  __shared__ float wL[FD * O];
  const int tid = threadIdx.x;
  for (int p = tid; p < FB; p += 256) {
    int b = p / FD;
    int f = p - b * FD;
    float v = (s == 0) ? X0[(size_t)n * FB + p]
                       : __half2float(XK[((size_t)(s - 1) * NN + n) * FB + p]);
    srcT[f * 36 + b] = v;
  }
  for (int p = tid; p < FD * O; p += 256) wL[p] = W[p];
  __syncthreads();
  constexpr int OG = O / 4;
  constexpr int BG = 256 / OG;
  constexpr int BPT = 32 / BG;
  const int og = tid % OG;
  const int bg = tid / OG;
  const int o0 = og * 4;
  const int b0 = bg * BPT;
  float acc[BPT][4];
#pragma unroll
  for (int i = 0; i < BPT; ++i)
#pragma unroll
    for (int j = 0; j < 4; ++j) acc[i][j] = 0.f;
  for (int f = 0; f < FD; ++f) {
    float4 wv = *reinterpret_cast<const float4*>(&wL[f * O + o0]);
    float wa[4] = {wv.x, wv.y, wv.z, wv.w};
#pragma unroll
    for (int bb = 0; bb < BPT; ++bb) {
      float sv = srcT[f * 36 + b0 + bb];
#pragma unroll
      for (int oo = 0; oo < 4; ++oo) acc[bb][oo] += sv * wa[oo];
    }
  }
#pragma unroll
  for (int bb = 0; bb < BPT; ++bb) {
    __half2* dst = reinterpret_cast<__half2*>(
        &XP[(((size_t)s * NN + n) * BB + b0 + bb) * O + o0]);
    dst[0] = __floats2half2_rn(acc[bb][0], acc[bb][1]);
    dst[1] = __floats2half2_rn(acc[bb][2], acc[bb][3]);
  }
}

// ---------------------------------------------------------------------------
// K4: attention (unchanged from round 1)
// ---------------------------------------------------------------------------
template <int O>
__global__ __launch_bounds__(256) void k_attend(
    const __half* __restrict__ XP, const float* __restrict__ Watt,
    const float* __restrict__ Watt1, float* __restrict__ XI,
    float* __restrict__ XS) {
  constexpr int QG = O / 4;
  constexpr int RG = 256 / QG;
  constexpr int RP = RG * 4;
  const int n = blockIdx.x;
  const int tid = threadIdx.x;
  __shared__ __half wattL[O * O];
  __shared__ float watt1L[O];
  __shared__ __half xpL[80 * O];
  __shared__ float sPart[RP * (QG + 1)];
  __shared__ float sL[80];
  __shared__ float aL[16][5];

  {
    const float2* wsrc =
        reinterpret_cast<const float2*>(Watt + (size_t)n * O * O);
    __half2* wdst = reinterpret_cast<__half2*>(wattL);
    for (int p = tid; p < O * O / 2; p += 256) {
      float2 wv = wsrc[p];
      wdst[p] = __floats2half2_rn(wv.x, wv.y);
    }
    for (int p = tid; p < O; p += 256) watt1L[p] = Watt1[(size_t)n * O + p];
  }

  const int qg = tid % QG;
  const int rg = tid / QG;
  const int q0 = qg * 4;

  for (int quad = 0; quad < 4; ++quad) {
    __syncthreads();
    {
      const uint32_t* xsrc = reinterpret_cast<const uint32_t*>(XP);
      uint32_t* xdst = reinterpret_cast<uint32_t*>(xpL);
      for (int p = tid; p < 80 * (O / 2); p += 256) {
        int r = p / (O / 2);
        int oh = p - r * (O / 2);
        int si = r >> 3;
        int bq = r & 7;
        size_t gi =
            (((size_t)(1 + si) * NN + n) * BB + quad * 8 + bq) * (O / 2) + oh;
        xdst[p] = xsrc[gi];
      }
    }
    __syncthreads();

    for (int pass = 0; pass * RP < 80; ++pass) {
      const int r0 = pass * RP + rg * 4;
      if (r0 < 80) {
        float h[4][4];
#pragma unroll
        for (int a = 0; a < 4; ++a)
#pragma unroll
          for (int b = 0; b < 4; ++b) h[a][b] = 0.f;
#pragma unroll 8
        for (int o = 0; o < O; o += 2) {
          const __half2* w0p =
              reinterpret_cast<const __half2*>(&wattL[o * O + q0]);
          const __half2* w1p =
              reinterpret_cast<const __half2*>(&wattL[(o + 1) * O + q0]);
          float2 wa = __half22float2(w0p[0]);
          float2 wb = __half22float2(w0p[1]);
          float2 wc = __half22float2(w1p[0]);
          float2 wd = __half22float2(w1p[1]);
          float w0[4] = {wa.x, wa.y, wb.x, wb.y};
          float w1[4] = {wc.x, wc.y, wd.x, wd.y};
#pragma unroll
          for (int rr = 0; rr < 4; ++rr) {
            float2 xf = __half22float2(
                *reinterpret_cast<const __half2*>(&xpL[(r0 + rr) * O + o]));
#pragma unroll
            for (int qq = 0; qq < 4; ++qq)
              h[rr][qq] += xf.x * w0[qq] + xf.y * w1[qq];
          }
        }
#pragma unroll
        for (int rr = 0; rr < 4; ++rr) {
          float pv = 0.f;
#pragma unroll
          for (int qq = 0; qq < 4; ++qq)
            pv += fmaxf(h[rr][qq], 0.f) * watt1L[q0 + qq];
          sPart[(rg * 4 + rr) * (QG + 1) + qg] = pv;
        }
      }
      __syncthreads();
      int nval = 80 - pass * RP;
      if (nval > RP) nval = RP;
      for (int r = tid; r < nval; r += 256) {
        float ssum = 0.f;
        for (int g = 0; g < QG; ++g) ssum += sPart[r * (QG + 1) + g];
        sL[pass * RP + r] = ssum;
      }
      __syncthreads();
    }

    if (tid < 16) {
      const int g = tid >> 3;
      const int bq = tid & 7;
      float sv[5];
#pragma unroll
      for (int k = 0; k < 5; ++k) sv[k] = sL[(g * 5 + k) * 8 + bq];
      float mx = sv[0];
#pragma unroll
      for (int k = 1; k < 5; ++k) mx = fmaxf(mx, sv[k]);
      float e[5], sum = 0.f;
#pragma unroll
      for (int k = 0; k < 5; ++k) {
        e[k] = expf(sv[k] - mx);
        sum += e[k];
      }
      float inv = 1.f / sum;
#pragma unroll
      for (int k = 0; k < 5; ++k) aL[tid][k] = e[k] * inv;
    }
    __syncthreads();

    constexpr int OGW = O / 4;
    const int o0w = (tid % OGW) * 4;
    for (int pr = tid / OGW; pr < 16; pr += 256 / OGW) {
      const int g = pr >> 3;
      const int bq = pr & 7;
      float o4[4] = {0.f, 0.f, 0.f, 0.f};
#pragma unroll
      for (int k = 0; k < 5; ++k) {
        float av = aL[pr][k];
        const __half2* xr = reinterpret_cast<const __half2*>(
            &xpL[((g * 5 + k) * 8 + bq) * O + o0w]);
        float2 x01 = __half22float2(xr[0]);
        float2 x23 = __half22float2(xr[1]);
        o4[0] += av * x01.x;
        o4[1] += av * x01.y;
        o4[2] += av * x23.x;
        o4[3] += av * x23.y;
      }
      float* dst =
          (g ? XS : XI) + ((size_t)(quad * 8 + bq) * NN + n) * O + o0w;
      *reinterpret_cast<float4*>(dst) = make_float4(o4[0], o4[1], o4[2], o4[3]);
    }
  }
}

// ---------------------------------------------------------------------------
// K5: ru output (unchanged)
// ---------------------------------------------------------------------------
__global__ __launch_bounds__(256) void k_wout_ru(
    const float* __restrict__ XI, const float* __restrict__ XS,
    const __half* __restrict__ XP, const float* __restrict__ Wout,
    const float* __restrict__ bias, const float* __restrict__ hx,
    float* __restrict__ RHX, float* __restrict__ UBUF) {
  const int n = blockIdx.x;
  const int tid = threadIdx.x;
  __shared__ float catT[384 * 36];
  for (int p = tid; p < 384 * 32; p += 256) {
    int b = p / 384;
    int op = p - b * 384;
    float v;
    if (op < 128)
      v = XI[((size_t)b * NN + n) * 128 + op];
    else if (op < 256)
      v = XS[((size_t)b * NN + n) * 128 + (op - 128)];
    else
      v = __half2float(XP[((size_t)n * BB + b) * 128 + (op - 256)]);
    catT[op * 36 + b] = v;
  }
  __syncthreads();
  const int og = tid & 31;
  const int bg = tid >> 5;
  const int o0 = og * 4;
  const int b0 = bg * 4;
  float acc[4][4];
#pragma unroll
  for (int i = 0; i < 4; ++i)
#pragma unroll
    for (int j = 0; j < 4; ++j) acc[i][j] = 0.f;
#pragma unroll 4
  for (int op = 0; op < 384; ++op) {
    float4 cv = *reinterpret_cast<const float4*>(&catT[op * 36 + b0]);
    float4 wv = *reinterpret_cast<const float4*>(&Wout[(size_t)op * 128 + o0]);
    float ca[4] = {cv.x, cv.y, cv.z, cv.w};
    float wa[4] = {wv.x, wv.y, wv.z, wv.w};
#pragma unroll
    for (int bb = 0; bb < 4; ++bb)
#pragma unroll
      for (int oo = 0; oo < 4; ++oo) acc[bb][oo] += ca[bb] * wa[oo];
  }
#pragma unroll
  for (int bb = 0; bb < 4; ++bb) {
    int b = b0 + bb;
    size_t base = (size_t)b * (NN * 64) + n * 64;
#pragma unroll
    for (int oo = 0; oo < 4; ++oo) {
      int o = o0 + oo;
      float val = acc[bb][oo] + bias[o];
      val = 1.f / (1.f + expf(-val));
      if (o < 64)
        RHX[base + o] = val * hx[base + o];
      else
        UBUF[base + (o - 64)] = val;
    }
  }
}

// ---------------------------------------------------------------------------
// K6: candidate output + final gate (unchanged)
// ---------------------------------------------------------------------------
__global__ __launch_bounds__(256) void k_wout_c(
    const float* __restrict__ XI, const float* __restrict__ XS,
    const __half* __restrict__ XP, const float* __restrict__ Wout,
    const float* __restrict__ bias, const float* __restrict__ UBUF,
    const float* __restrict__ hx, float* __restrict__ out) {
  const int n = blockIdx.x;
  const int tid = threadIdx.x;
  __shared__ float catT[192 * 36];
  for (int p = tid; p < 192 * 32; p += 256) {
    int b = p / 192;
    int op = p - b * 192;
    float v;
    if (op < 64)
      v = XI[((size_t)b * NN + n) * 64 + op];
    else if (op < 128)
      v = XS[((size_t)b * NN + n) * 64 + (op - 64)];
    else
      v = __half2float(XP[((size_t)n * BB + b) * 64 + (op - 128)]);
    catT[op * 36 + b] = v;
  }
  __syncthreads();
  const int og = tid & 15;
  const int bg = tid >> 4;
  const int o0 = og * 4;
  const int b0 = bg * 2;
  float acc[2][4];
#pragma unroll
  for (int i = 0; i < 2; ++i)
#pragma unroll
    for (int j = 0; j < 4; ++j) acc[i][j] = 0.f;
#pragma unroll 4
  for (int op = 0; op < 192; ++op) {
    float2 cv = *reinterpret_cast<const float2*>(&catT[op * 36 + b0]);
    float4 wv = *reinterpret_cast<const float4*>(&Wout[(size_t)op * 64 + o0]);
    float wa[4] = {wv.x, wv.y, wv.z, wv.w};
#pragma unroll
    for (int oo = 0; oo < 4; ++oo) {
      acc[0][oo] += cv.x * wa[oo];
      acc[1][oo] += cv.y * wa[oo];
    }
  }
#pragma unroll
  for (int bb = 0; bb < 2; ++bb) {
    int b = b0 + bb;
#pragma unroll
    for (int oo = 0; oo < 4; ++oo) {
      int o = o0 + oo;
      float cval = tanhf(acc[bb][oo] + bias[o]);
      size_t idx = (size_t)b * (NN * 64) + n * 64 + o;
      float u = UBUF[idx];
      out[idx] = u * hx[idx] + (1.f - u) * cval;
    }
  }
}

// ---------------------------------------------------------------------------
extern "C" void kernel_launch(void* const* d_in, const int* in_sizes, int n_in,
                              void* d_out, int out_size, void* d_ws,
                              size_t ws_size, hipStream_t stream) {
  const float* inputs   = (const float*)d_in[0];
  const float* hx       = (const float*)d_in[1];
  const float* adj      = (const float*)d_in[2];
  const float* mask     = (const float*)d_in[3];
  const float* W_ru     = (const float*)d_in[4];
  const float* Watt_ru  = (const float*)d_in[5];
  const float* Watt1_ru = (const float*)d_in[6];
  const float* Wout_ru  = (const float*)d_in[7];
  const float* b_ru     = (const float*)d_in[8];
  const float* W_c      = (const float*)d_in[9];
  const float* Watt_c   = (const float*)d_in[10];
  const float* Watt1_c  = (const float*)d_in[11];
  const float* Wout_c   = (const float*)d_in[12];
  const float* b_c      = (const float*)d_in[13];

  // workspace arena (~186.4 MB):
  //   X0    fp32 [1024][2112]          @ 0           (8,650,752)
  //   XK    fp16 [10][1024][2112]      @ 8,650,752   (43,253,760)
  //     XI  fp32 [32][1024][128] aliases XK (dead after k_proj)
  //     XS  fp32 aliases XK+16,777,216
  //   XP    fp16 [11][1024][32][128]   @ 51,904,512  (92,274,688)
  //   RHX   fp32                       @ 144,179,200 (8,388,608)
  //   UBUF  fp32                       @ 152,567,808 (8,388,608)
  //   A_all fp16 [10][1024][1024]      @ 160,956,416 (20,971,520)
  //   X0T   fp16 [2176][1024]          @ 181,927,936 (4,456,448) end 186,384,384
  char* ws = (char*)d_ws;
  float*     X0    = (float*)(ws);
  __half*    XK    = (__half*)(ws + 8650752);
  float*     XI    = (float*)(ws + 8650752);
  float*     XS    = (float*)(ws + 8650752 + 16777216);
  __half*    XP    = (__half*)(ws + 51904512);
  float*     RHX   = (float*)(ws + 144179200);
  float*     UBUF  = (float*)(ws + 152567808);
  _Float16*  A_all = (_Float16*)(ws + 160956416);
  _Float16*  X0T   = (_Float16*)(ws + 181927936);
  float*     out   = (float*)d_out;

  k_build_amats<<<1024, 256, 0, stream>>>(adj, mask, A_all);

  // ---- gate gconv (O = 2U = 128) ----
  k_build_x0<<<8448, 256, 0, stream>>>(inputs, hx, X0);
  k_build_x0t<<<dim3(32, 16), 256, 0, stream>>>(inputs, hx, X0T);
  k_supports_mfma<<<dim3(17, 80), 256, 0, stream>>>(A_all, X0T, XK);
  k_proj<128><<<dim3(1024, 11), 256, 0, stream>>>(X0, XK, W_ru, XP);
  k_attend<128><<<1024, 256, 0, stream>>>(XP, Watt_ru, Watt1_ru, XI, XS);
  k_wout_ru<<<1024, 256, 0, stream>>>(XI, XS, XP, Wout_ru, b_ru, hx, RHX, UBUF);
  // ---- candidate gconv (O = U = 64), state = r*hx ----
  k_build_x0<<<8448, 256, 0, stream>>>(inputs, RHX, X0);
  k_build_x0t<<<dim3(32, 16), 256, 0, stream>>>(inputs, RHX, X0T);
  k_supports_mfma<<<dim3(17, 80), 256, 0, stream>>>(A_all, X0T, XK);
  k_proj<64><<<dim3(1024, 11), 256, 0, stream>>>(X0, XK, W_c, XP);
  k_attend<64><<<1024, 256, 0, stream>>>(XP, Watt_c, Watt1_c, XI, XS);
  k_wout_c<<<1024, 256, 0, stream>>>(XI, XS, XP, Wout_c, b_c, UBUF, hx, out);
}

// Round 3
// 572.483 us; speedup vs baseline: 6.0241x; 1.5183x over previous
//
#include <hip/hip_runtime.h>
#include <hip/hip_fp16.h>
#include <cstdint>
#include <cstddef>

#define NN 1024   // nodes
#define BB 32     // batch
#define FD 66     // features per node (2 + 64)
#define FB 2112   // FD*BB

typedef _Float16 f16x8 __attribute__((ext_vector_type(8)));
typedef _Float16 f16x4 __attribute__((ext_vector_type(4)));
typedef float f32x4 __attribute__((ext_vector_type(4)));

__device__ __forceinline__ void load_lds16(const void* g, void* l) {
  __builtin_amdgcn_global_load_lds(
      (const __attribute__((address_space(1))) void*)g,
      (__attribute__((address_space(3))) void*)l, 16, 0, 0);
}

// ---------------------------------------------------------------------------
// K0: build the 10 support matrices (shared by both gconvs), fp16.
// ---------------------------------------------------------------------------
__global__ __launch_bounds__(256) void k_build_amats(
    const float* __restrict__ adj, const float* __restrict__ mask,
    _Float16* __restrict__ A) {
  int q = blockIdx.x * 256 + threadIdx.x;  // 0..262143 quads
  int i = q >> 8;
  int j0 = (q & 255) << 2;
  size_t off = (size_t)i * 1024 + j0;
  float4 a0 = *(const float4*)(adj + off);
  float4 a1 = *(const float4*)(adj + (1u << 20) + off);
  f16x4 r;
  r[0] = a0.x; r[1] = a0.y; r[2] = a0.z; r[3] = a0.w;
  *(f16x4*)(A + off) = r;
  r[0] = a1.x; r[1] = a1.y; r[2] = a1.z; r[3] = a1.w;
  *(f16x4*)(A + (size_t)9 * 1048576 + off) = r;
#pragma unroll
  for (int l = 0; l < 8; ++l) {
    float4 mk = *(const float4*)(mask + (size_t)l * 1048576 + off);
    float4 base = (l < 4) ? a0 : a1;
    r[0] = mk.x * base.x; r[1] = mk.y * base.y;
    r[2] = mk.z * base.z; r[3] = mk.w * base.w;
    *(f16x4*)(A + (size_t)(l + 1) * 1048576 + off) = r;
  }
}

// ---------------------------------------------------------------------------
// K1: build x0 fp32.  X0[n*FB + b*FD + f] = x[b,n,f]  (for proj s=0)
// ---------------------------------------------------------------------------
__global__ __launch_bounds__(256) void k_build_x0(
    const float* __restrict__ inp, const float* __restrict__ state,
    float* __restrict__ X0) {
  int idx = blockIdx.x * 256 + threadIdx.x;
  if (idx >= NN * FB) return;
  int n = idx / FB;
  int r = idx - n * FB;
  int b = r / FD;
  int f = r - b * FD;
  float v = (f < 2) ? inp[b * (NN * 2) + n * 2 + f]
                    : state[(size_t)b * (NN * 64) + n * 64 + (f - 2)];
  X0[idx] = v;
}

// ---------------------------------------------------------------------------
// K1b: build X0^T fp16, padded to 2176 rows.  X0T[(b*66+f)*1024 + n]
// ---------------------------------------------------------------------------
__global__ __launch_bounds__(256) void k_build_x0t(
    const float* __restrict__ inp, const float* __restrict__ state,
    _Float16* __restrict__ X0T) {
  __shared__ float tile[64 * 65];
  const int b = blockIdx.x;        // 0..31
  const int n0 = blockIdx.y * 64;  // 0..960
  const int tid = threadIdx.x;
  for (int p = tid; p < 4096; p += 256) {
    int nn = p >> 6, f = p & 63;
    tile[f * 65 + nn] = state[(size_t)b * 65536 + (n0 + nn) * 64 + f];
  }
  __syncthreads();
  for (int p = tid; p < 4096; p += 256) {
    int f = p >> 6, nn = p & 63;
    X0T[(size_t)(b * 66 + 2 + f) * 1024 + n0 + nn] = (_Float16)tile[f * 65 + nn];
  }
  if (tid < 128) {
    int f = tid >> 6, nn = tid & 63;
    X0T[(size_t)(b * 66 + f) * 1024 + n0 + nn] =
        (_Float16)inp[(size_t)b * 2048 + (n0 + nn) * 2 + f];
  }
}

// ---------------------------------------------------------------------------
// K2: supports GEMM via MFMA (unchanged from round 2).
// ---------------------------------------------------------------------------
__global__ __launch_bounds__(256, 2) void k_supports_mfma(
    const _Float16* __restrict__ A, const _Float16* __restrict__ BT,
    __half* __restrict__ XK) {
  __shared__ _Float16 ldsA[2][4096];  // [buf][128 rows][32 k]
  __shared__ _Float16 ldsB[2][4096];
  const int tid = threadIdx.x;
  const int bn = blockIdx.x;  // 0..16 (col tiles, last partial)
  const int bm = blockIdx.y;  // 0..79
  const int l = tid & 63;
  const int w = tid >> 6;
  const int wr = w >> 1, wc = w & 1;

  const int t0 = tid, t1 = 256 + tid;
  const int r0 = t0 >> 2, q0 = (t0 & 3) ^ (r0 & 3);
  const int r1 = t1 >> 2, q1 = (t1 & 3) ^ (r1 & 3);
  const _Float16* gA0 = A + ((size_t)(bm * 128 + r0)) * 1024 + q0 * 8;
  const _Float16* gA1 = A + ((size_t)(bm * 128 + r1)) * 1024 + q1 * 8;
  const _Float16* gB0 = BT + ((size_t)(bn * 128 + r0)) * 1024 + q0 * 8;
  const _Float16* gB1 = BT + ((size_t)(bn * 128 + r1)) * 1024 + q1 * 8;

  const int ps = ((l >> 4) ^ (l & 3)) * 8;  // physical slot * 8
  int offA[4], offB[4];
#pragma unroll
  for (int i = 0; i < 4; ++i) {
    offA[i] = (wr * 64 + i * 16 + (l & 15)) * 32 + ps;
    offB[i] = (wc * 64 + i * 16 + (l & 15)) * 32 + ps;
  }

  f32x4 acc[4][4];
#pragma unroll
  for (int i = 0; i < 4; ++i)
#pragma unroll
    for (int j = 0; j < 4; ++j) acc[i][j] = (f32x4){0.f, 0.f, 0.f, 0.f};

  load_lds16(gA0, &ldsA[0][0] + t0 * 8);
  load_lds16(gA1, &ldsA[0][0] + t1 * 8);
  load_lds16(gB0, &ldsB[0][0] + t0 * 8);
  load_lds16(gB1, &ldsB[0][0] + t1 * 8);

  int buf = 0;
  for (int kt = 0; kt < 32; ++kt) {
    __syncthreads();
    if (kt + 1 < 32) {
      int k0 = (kt + 1) * 32;
      load_lds16(gA0 + k0, &ldsA[buf ^ 1][0] + t0 * 8);
      load_lds16(gA1 + k0, &ldsA[buf ^ 1][0] + t1 * 8);
      load_lds16(gB0 + k0, &ldsB[buf ^ 1][0] + t0 * 8);
      load_lds16(gB1 + k0, &ldsB[buf ^ 1][0] + t1 * 8);
    }
    f16x8 af[4], bf[4];
#pragma unroll
    for (int i = 0; i < 4; ++i)
      af[i] = *(const f16x8*)(&ldsA[buf][offA[i]]);
#pragma unroll
    for (int i = 0; i < 4; ++i)
      bf[i] = *(const f16x8*)(&ldsB[buf][offB[i]]);
#pragma unroll
    for (int i = 0; i < 4; ++i)
#pragma unroll
      for (int j = 0; j < 4; ++j)
        acc[i][j] = __builtin_amdgcn_mfma_f32_16x16x32_f16(af[i], bf[j],
                                                           acc[i][j], 0, 0, 0);
    buf ^= 1;
  }

#pragma unroll
  for (int i = 0; i < 4; ++i) {
    int R = bm * 128 + wr * 64 + i * 16 + (l >> 4) * 4;
#pragma unroll
    for (int j = 0; j < 4; ++j) {
      int colb = bn * 128 + wc * 64 + j * 16;
      if (colb >= FB) continue;
      int col = colb + (l & 15);
#pragma unroll
      for (int r = 0; r < 4; ++r)
        XK[(size_t)(R + r) * FB + col] = __float2half(acc[i][j][r]);
    }
  }
}

// ---------------------------------------------------------------------------
// K3: projection (unchanged).
// ---------------------------------------------------------------------------
template <int O>
__global__ __launch_bounds__(256) void k_proj(
    const float* __restrict__ X0, const __half* __restrict__ XK,
    const float* __restrict__ W, __half* __restrict__ XP) {
  const int n = blockIdx.x;
  const int s = blockIdx.y;  // 0..10
  __shared__ float srcT[FD * 36];
  __shared__ float wL[FD * O];
  const int tid = threadIdx.x;
  for (int p = tid; p < FB; p += 256) {
    int b = p / FD;
    int f = p - b * FD;
    float v = (s == 0) ? X0[(size_t)n * FB + p]
                       : __half2float(XK[((size_t)(s - 1) * NN + n) * FB + p]);
    srcT[f * 36 + b] = v;
  }
  for (int p = tid; p < FD * O; p += 256) wL[p] = W[p];
  __syncthreads();
  constexpr int OG = O / 4;
  constexpr int BG = 256 / OG;
  constexpr int BPT = 32 / BG;
  const int og = tid % OG;
  const int bg = tid / OG;
  const int o0 = og * 4;
  const int b0 = bg * BPT;
  float acc[BPT][4];
#pragma unroll
  for (int i = 0; i < BPT; ++i)
#pragma unroll
    for (int j = 0; j < 4; ++j) acc[i][j] = 0.f;
  for (int f = 0; f < FD; ++f) {
    float4 wv = *reinterpret_cast<const float4*>(&wL[f * O + o0]);
    float wa[4] = {wv.x, wv.y, wv.z, wv.w};
#pragma unroll
    for (int bb = 0; bb < BPT; ++bb) {
      float sv = srcT[f * 36 + b0 + bb];
#pragma unroll
      for (int oo = 0; oo < 4; ++oo) acc[bb][oo] += sv * wa[oo];
    }
  }
#pragma unroll
  for (int bb = 0; bb < BPT; ++bb) {
    __half2* dst = reinterpret_cast<__half2*>(
        &XP[(((size_t)s * NN + n) * BB + b0 + bb) * O + o0]);
    dst[0] = __floats2half2_rn(acc[bb][0], acc[bb][1]);
    dst[1] = __floats2half2_rn(acc[bb][2], acc[bb][3]);
  }
}

// ---------------------------------------------------------------------------
// K4: attention via MFMA.  Per node n, per group g (i/s):
//   h^T[q][row] = sum_o WattT[q][o] * xp[row][o]   (A = WattT in regs, fp16)
//   s[row] = sum_q relu(h) * watt1[q]  (per-lane FMA + shfl_xor reduce)
//   softmax over 5 supports per b; out[b][o] = sum_si a * xp[row(si,b)][o]
// rows: row = si*32 + b (160 per group).  xpL fp16 with 16B-slot XOR swizzle.
// ---------------------------------------------------------------------------
template <int O>
__global__ __launch_bounds__(256) void k_attend_mfma(
    const __half* __restrict__ XP, const float* __restrict__ Watt,
    const float* __restrict__ Watt1, float* __restrict__ XI,
    float* __restrict__ XS) {
  constexpr int MTW = O / 64;       // q-tiles per wave (2 or 1)
  constexpr int KS = O / 32;        // k-steps (4 or 2)
  constexpr int SLOTS = O / 8;      // 16B slots per row (16 or 8)
  constexpr int SWZ = SLOTS - 1;
  constexpr int OH = O / 2;         // u32 per row
  const int n = blockIdx.x;
  const int tid = threadIdx.x;
  const int l = tid & 63;
  const int w = tid >> 6;

  __shared__ _Float16 xpL[160 * O];
  __shared__ float sPartL[4][160];
  __shared__ float aL[32][5];

  // ---- A-frags (WattT) + watt1, in registers, reused for both groups ----
  const int qbase = w * (O / 4);
  f16x8 afr[MTW][KS];
#pragma unroll
  for (int mt = 0; mt < MTW; ++mt) {
    const int q = qbase + mt * 16 + (l & 15);
#pragma unroll
    for (int ks = 0; ks < KS; ++ks) {
#pragma unroll
      for (int e = 0; e < 8; ++e) {
        int o = ks * 32 + (l >> 4) * 8 + e;
        afr[mt][ks][e] = (_Float16)Watt[((size_t)n * O + o) * O + q];
      }
    }
  }
  float wt1[MTW][4];
#pragma unroll
  for (int mt = 0; mt < MTW; ++mt)
#pragma unroll
    for (int r = 0; r < 4; ++r)
      wt1[mt][r] = Watt1[(size_t)n * O + qbase + mt * 16 + (l >> 4) * 4 + r];

  for (int g = 0; g < 2; ++g) {
    if (g) __syncthreads();  // wsum readers of xpL done
    // ---- stage xp (5 supports of this group) into swizzled LDS ----
    {
      const uint32_t* xsrc = reinterpret_cast<const uint32_t*>(XP);
      uint32_t* xdst = reinterpret_cast<uint32_t*>(xpL);
      for (int p = tid; p < 160 * OH; p += 256) {
        int row = p / OH;
        int oh = p - row * OH;
        int slot = oh >> 2;
        int phys = slot ^ (row & SWZ);
        int si = row >> 5, b = row & 31;
        size_t gi = (((size_t)(1 + g * 5 + si) * NN + n) * BB + b) * OH + oh;
        xdst[row * OH + phys * 4 + (oh & 3)] = xsrc[gi];
      }
    }
    __syncthreads();

    // ---- h^T MFMA + s reduction ----
    for (int nt = 0; nt < 10; ++nt) {
      f32x4 acc[MTW];
#pragma unroll
      for (int mt = 0; mt < MTW; ++mt) acc[mt] = (f32x4){0.f, 0.f, 0.f, 0.f};
      const int row = nt * 16 + (l & 15);
#pragma unroll
      for (int ks = 0; ks < KS; ++ks) {
        int phys = (ks * 4 + (l >> 4)) ^ (row & SWZ);
        f16x8 bf = *(const f16x8*)(&xpL[row * O + phys * 8]);
#pragma unroll
        for (int mt = 0; mt < MTW; ++mt)
          acc[mt] = __builtin_amdgcn_mfma_f32_16x16x32_f16(afr[mt][ks], bf,
                                                           acc[mt], 0, 0, 0);
      }
      float sp = 0.f;
#pragma unroll
      for (int mt = 0; mt < MTW; ++mt)
#pragma unroll
        for (int r = 0; r < 4; ++r)
          sp += fmaxf(acc[mt][r], 0.f) * wt1[mt][r];
      sp += __shfl_xor(sp, 16);
      sp += __shfl_xor(sp, 32);
      if (l < 16) sPartL[w][nt * 16 + l] = sp;
    }
    __syncthreads();

    // ---- softmax over the 5 supports per b ----
    if (tid < 32) {
      const int b = tid;
      float sv[5];
#pragma unroll
      for (int k = 0; k < 5; ++k) {
        int row = k * 32 + b;
        sv[k] = sPartL[0][row] + sPartL[1][row] + sPartL[2][row] +
                sPartL[3][row];
      }
      float mx = sv[0];
#pragma unroll
      for (int k = 1; k < 5; ++k) mx = fmaxf(mx, sv[k]);
      float e[5], sum = 0.f;
#pragma unroll
      for (int k = 0; k < 5; ++k) {
        e[k] = expf(sv[k] - mx);
        sum += e[k];
      }
      float inv = 1.f / sum;
#pragma unroll
      for (int k = 0; k < 5; ++k) aL[b][k] = e[k] * inv;
    }
    __syncthreads();

    // ---- weighted sum: out[b][o] = sum_si a * xp[si*32+b][o] ----
    float* gout = g ? XS : XI;
    for (int it = 0; it < SLOTS * 32 / 256; ++it) {
      int idx = it * 256 + tid;
      int b = idx & 31;
      int sc = idx >> 5;  // logical 16B slot = 8 o's
      float o8[8] = {0.f, 0.f, 0.f, 0.f, 0.f, 0.f, 0.f, 0.f};
#pragma unroll
      for (int si = 0; si < 5; ++si) {
        int row = si * 32 + b;
        int phys = sc ^ (row & SWZ);
        f16x8 xv = *(const f16x8*)(&xpL[row * O + phys * 8]);
        float a = aL[b][si];
#pragma unroll
        for (int j = 0; j < 8; ++j) o8[j] += a * (float)xv[j];
      }
      float* dst = gout + ((size_t)b * NN + n) * O + sc * 8;
      *reinterpret_cast<float4*>(dst) = make_float4(o8[0], o8[1], o8[2], o8[3]);
      *reinterpret_cast<float4*>(dst + 4) =
          make_float4(o8[4], o8[5], o8[6], o8[7]);
    }
  }
}

// ---------------------------------------------------------------------------
// K5: ru output (unchanged)
// ---------------------------------------------------------------------------
__global__ __launch_bounds__(256) void k_wout_ru(
    const float* __restrict__ XI, const float* __restrict__ XS,
    const __half* __restrict__ XP, const float* __restrict__ Wout,
    const float* __restrict__ bias, const float* __restrict__ hx,
    float* __restrict__ RHX, float* __restrict__ UBUF) {
  const int n = blockIdx.x;
  const int tid = threadIdx.x;
  __shared__ float catT[384 * 36];
  for (int p = tid; p < 384 * 32; p += 256) {
    int b = p / 384;
    int op = p - b * 384;
    float v;
    if (op < 128)
      v = XI[((size_t)b * NN + n) * 128 + op];
    else if (op < 256)
      v = XS[((size_t)b * NN + n) * 128 + (op - 128)];
    else
      v = __half2float(XP[((size_t)n * BB + b) * 128 + (op - 256)]);
    catT[op * 36 + b] = v;
  }
  __syncthreads();
  const int og = tid & 31;
  const int bg = tid >> 5;
  const int o0 = og * 4;
  const int b0 = bg * 4;
  float acc[4][4];
#pragma unroll
  for (int i = 0; i < 4; ++i)
#pragma unroll
    for (int j = 0; j < 4; ++j) acc[i][j] = 0.f;
#pragma unroll 4
  for (int op = 0; op < 384; ++op) {
    float4 cv = *reinterpret_cast<const float4*>(&catT[op * 36 + b0]);
    float4 wv = *reinterpret_cast<const float4*>(&Wout[(size_t)op * 128 + o0]);
    float ca[4] = {cv.x, cv.y, cv.z, cv.w};
    float wa[4] = {wv.x, wv.y, wv.z, wv.w};
#pragma unroll
    for (int bb = 0; bb < 4; ++bb)
#pragma unroll
      for (int oo = 0; oo < 4; ++oo) acc[bb][oo] += ca[bb] * wa[oo];
  }
#pragma unroll
  for (int bb = 0; bb < 4; ++bb) {
    int b = b0 + bb;
    size_t base = (size_t)b * (NN * 64) + n * 64;
#pragma unroll
    for (int oo = 0; oo < 4; ++oo) {
      int o = o0 + oo;
      float val = acc[bb][oo] + bias[o];
      val = 1.f / (1.f + expf(-val));
      if (o < 64)
        RHX[base + o] = val * hx[base + o];
      else
        UBUF[base + (o - 64)] = val;
    }
  }
}

// ---------------------------------------------------------------------------
// K6: candidate output + final gate (unchanged)
// ---------------------------------------------------------------------------
__global__ __launch_bounds__(256) void k_wout_c(
    const float* __restrict__ XI, const float* __restrict__ XS,
    const __half* __restrict__ XP, const float* __restrict__ Wout,
    const float* __restrict__ bias, const float* __restrict__ UBUF,
    const float* __restrict__ hx, float* __restrict__ out) {
  const int n = blockIdx.x;
  const int tid = threadIdx.x;
  __shared__ float catT[192 * 36];
  for (int p = tid; p < 192 * 32; p += 256) {
    int b = p / 192;
    int op = p - b * 192;
    float v;
    if (op < 64)
      v = XI[((size_t)b * NN + n) * 64 + op];
    else if (op < 128)
      v = XS[((size_t)b * NN + n) * 64 + (op - 64)];
    else
      v = __half2float(XP[((size_t)n * BB + b) * 64 + (op - 128)]);
    catT[op * 36 + b] = v;
  }
  __syncthreads();
  const int og = tid & 15;
  const int bg = tid >> 4;
  const int o0 = og * 4;
  const int b0 = bg * 2;
  float acc[2][4];
#pragma unroll
  for (int i = 0; i < 2; ++i)
#pragma unroll
    for (int j = 0; j < 4; ++j) acc[i][j] = 0.f;
#pragma unroll 4
  for (int op = 0; op < 192; ++op) {
    float2 cv = *reinterpret_cast<const float2*>(&catT[op * 36 + b0]);
    float4 wv = *reinterpret_cast<const float4*>(&Wout[(size_t)op * 64 + o0]);
    float wa[4] = {wv.x, wv.y, wv.z, wv.w};
#pragma unroll
    for (int oo = 0; oo < 4; ++oo) {
      acc[0][oo] += cv.x * wa[oo];
      acc[1][oo] += cv.y * wa[oo];
    }
  }
#pragma unroll
  for (int bb = 0; bb < 2; ++bb) {
    int b = b0 + bb;
#pragma unroll
    for (int oo = 0; oo < 4; ++oo) {
      int o = o0 + oo;
      float cval = tanhf(acc[bb][oo] + bias[o]);
      size_t idx = (size_t)b * (NN * 64) + n * 64 + o;
      float u = UBUF[idx];
      out[idx] = u * hx[idx] + (1.f - u) * cval;
    }
  }
}

// ---------------------------------------------------------------------------
extern "C" void kernel_launch(void* const* d_in, const int* in_sizes, int n_in,
                              void* d_out, int out_size, void* d_ws,
                              size_t ws_size, hipStream_t stream) {
  const float* inputs   = (const float*)d_in[0];
  const float* hx       = (const float*)d_in[1];
  const float* adj      = (const float*)d_in[2];
  const float* mask     = (const float*)d_in[3];
  const float* W_ru     = (const float*)d_in[4];
  const float* Watt_ru  = (const float*)d_in[5];
  const float* Watt1_ru = (const float*)d_in[6];
  const float* Wout_ru  = (const float*)d_in[7];
  const float* b_ru     = (const float*)d_in[8];
  const float* W_c      = (const float*)d_in[9];
  const float* Watt_c   = (const float*)d_in[10];
  const float* Watt1_c  = (const float*)d_in[11];
  const float* Wout_c   = (const float*)d_in[12];
  const float* b_c      = (const float*)d_in[13];

  // workspace arena (~186.4 MB), same as round 2
  char* ws = (char*)d_ws;
  float*     X0    = (float*)(ws);
  __half*    XK    = (__half*)(ws + 8650752);
  float*     XI    = (float*)(ws + 8650752);
  float*     XS    = (float*)(ws + 8650752 + 16777216);
  __half*    XP    = (__half*)(ws + 51904512);
  float*     RHX   = (float*)(ws + 144179200);
  float*     UBUF  = (float*)(ws + 152567808);
  _Float16*  A_all = (_Float16*)(ws + 160956416);
  _Float16*  X0T   = (_Float16*)(ws + 181927936);
  float*     out   = (float*)d_out;

  k_build_amats<<<1024, 256, 0, stream>>>(adj, mask, A_all);

  // ---- gate gconv (O = 2U = 128) ----
  k_build_x0<<<8448, 256, 0, stream>>>(inputs, hx, X0);
  k_build_x0t<<<dim3(32, 16), 256, 0, stream>>>(inputs, hx, X0T);
  k_supports_mfma<<<dim3(17, 80), 256, 0, stream>>>(A_all, X0T, XK);
  k_proj<128><<<dim3(1024, 11), 256, 0, stream>>>(X0, XK, W_ru, XP);
  k_attend_mfma<128><<<1024, 256, 0, stream>>>(XP, Watt_ru, Watt1_ru, XI, XS);
  k_wout_ru<<<1024, 256, 0, stream>>>(XI, XS, XP, Wout_ru, b_ru, hx, RHX, UBUF);
  // ---- candidate gconv (O = U = 64), state = r*hx ----
  k_build_x0<<<8448, 256, 0, stream>>>(inputs, RHX, X0);
  k_build_x0t<<<dim3(32, 16), 256, 0, stream>>>(inputs, RHX, X0T);
  k_supports_mfma<<<dim3(17, 80), 256, 0, stream>>>(A_all, X0T, XK);
  k_proj<64><<<dim3(1024, 11), 256, 0, stream>>>(X0, XK, W_c, XP);
  k_attend_mfma<64><<<1024, 256, 0, stream>>>(XP, Watt_c, Watt1_c, XI, XS);
  k_wout_c<<<1024, 256, 0, stream>>>(XI, XS, XP, Wout_c, b_c, UBUF, hx, out);
}

// Round 5
// 480.985 us; speedup vs baseline: 7.1701x; 1.1902x over previous
//
#include <hip/hip_runtime.h>
#include <hip/hip_fp16.h>
#include <cstdint>
#include <cstddef>

#define NN 1024   // nodes
#define BB 32     // batch
#define FD 66     // features per node (2 + 64)
#define FB 2112   // FD*BB

typedef _Float16 f16x8 __attribute__((ext_vector_type(8)));
typedef _Float16 f16x4 __attribute__((ext_vector_type(4)));
typedef float f32x4 __attribute__((ext_vector_type(4)));

__device__ __forceinline__ void load_lds16(const void* g, void* l) {
  __builtin_amdgcn_global_load_lds(
      (const __attribute__((address_space(1))) void*)g,
      (__attribute__((address_space(3))) void*)l, 16, 0, 0);
}

// ---------------------------------------------------------------------------
// K0: build the 10 support matrices (shared by both gconvs), fp16.
// ---------------------------------------------------------------------------
__global__ __launch_bounds__(256) void k_build_amats(
    const float* __restrict__ adj, const float* __restrict__ mask,
    _Float16* __restrict__ A) {
  int q = blockIdx.x * 256 + threadIdx.x;  // 0..262143 quads
  int i = q >> 8;
  int j0 = (q & 255) << 2;
  size_t off = (size_t)i * 1024 + j0;
  float4 a0 = *(const float4*)(adj + off);
  float4 a1 = *(const float4*)(adj + (1u << 20) + off);
  f16x4 r;
  r[0] = a0.x; r[1] = a0.y; r[2] = a0.z; r[3] = a0.w;
  *(f16x4*)(A + off) = r;
  r[0] = a1.x; r[1] = a1.y; r[2] = a1.z; r[3] = a1.w;
  *(f16x4*)(A + (size_t)9 * 1048576 + off) = r;
#pragma unroll
  for (int l = 0; l < 8; ++l) {
    float4 mk = *(const float4*)(mask + (size_t)l * 1048576 + off);
    float4 base = (l < 4) ? a0 : a1;
    r[0] = mk.x * base.x; r[1] = mk.y * base.y;
    r[2] = mk.z * base.z; r[3] = mk.w * base.w;
    *(f16x4*)(A + (size_t)(l + 1) * 1048576 + off) = r;
  }
}

// ---------------------------------------------------------------------------
// K0b: transpose+convert Wout matrices to fp16 hi/lo [O][K]
// ---------------------------------------------------------------------------
__global__ __launch_bounds__(256) void k_prep_wout(
    const float* __restrict__ Wru, const float* __restrict__ Wc,
    _Float16* __restrict__ WThru, _Float16* __restrict__ WTlru,
    _Float16* __restrict__ WThc, _Float16* __restrict__ WTlc) {
  int id = blockIdx.x * 256 + threadIdx.x;
  if (id < 128 * 384) {
    int o = id & 127, k = id >> 7;
    float w = Wru[k * 128 + o];
    _Float16 h = (_Float16)w;
    WThru[o * 384 + k] = h;
    WTlru[o * 384 + k] = (_Float16)(w - (float)h);
  } else {
    int id2 = id - 128 * 384;
    if (id2 < 64 * 192) {
      int o = id2 & 63, k = id2 >> 6;
      float w = Wc[k * 64 + o];
      _Float16 h = (_Float16)w;
      WThc[o * 192 + k] = h;
      WTlc[o * 192 + k] = (_Float16)(w - (float)h);
    }
  }
}

// ---------------------------------------------------------------------------
// K1: build x0 fp32.  X0[n*FB + b*FD + f] = x[b,n,f]  (for proj s=0)
// ---------------------------------------------------------------------------
__global__ __launch_bounds__(256) void k_build_x0(
    const float* __restrict__ inp, const float* __restrict__ state,
    float* __restrict__ X0) {
  int idx = blockIdx.x * 256 + threadIdx.x;
  if (idx >= NN * FB) return;
  int n = idx / FB;
  int r = idx - n * FB;
  int b = r / FD;
  int f = r - b * FD;
  float v = (f < 2) ? inp[b * (NN * 2) + n * 2 + f]
                    : state[(size_t)b * (NN * 64) + n * 64 + (f - 2)];
  X0[idx] = v;
}

// ---------------------------------------------------------------------------
// K1b: build X0^T fp16, padded to 2176 rows.  X0T[(b*66+f)*1024 + n]
// ---------------------------------------------------------------------------
__global__ __launch_bounds__(256) void k_build_x0t(
    const float* __restrict__ inp, const float* __restrict__ state,
    _Float16* __restrict__ X0T) {
  __shared__ float tile[64 * 65];
  const int b = blockIdx.x;        // 0..31
  const int n0 = blockIdx.y * 64;  // 0..960
  const int tid = threadIdx.x;
  for (int p = tid; p < 4096; p += 256) {
    int nn = p >> 6, f = p & 63;
    tile[f * 65 + nn] = state[(size_t)b * 65536 + (n0 + nn) * 64 + f];
  }
  __syncthreads();
  for (int p = tid; p < 4096; p += 256) {
    int f = p >> 6, nn = p & 63;
    X0T[(size_t)(b * 66 + 2 + f) * 1024 + n0 + nn] = (_Float16)tile[f * 65 + nn];
  }
  if (tid < 128) {
    int f = tid >> 6, nn = tid & 63;
    X0T[(size_t)(b * 66 + f) * 1024 + n0 + nn] =
        (_Float16)inp[(size_t)b * 2048 + (n0 + nn) * 2 + f];
  }
}

// ---------------------------------------------------------------------------
// K2: supports GEMM via MFMA (unchanged).
// ---------------------------------------------------------------------------
__global__ __launch_bounds__(256, 2) void k_supports_mfma(
    const _Float16* __restrict__ A, const _Float16* __restrict__ BT,
    __half* __restrict__ XK) {
  __shared__ _Float16 ldsA[2][4096];  // [buf][128 rows][32 k]
  __shared__ _Float16 ldsB[2][4096];
  const int tid = threadIdx.x;
  const int bn = blockIdx.x;  // 0..16 (col tiles, last partial)
  const int bm = blockIdx.y;  // 0..79
  const int l = tid & 63;
  const int w = tid >> 6;
  const int wr = w >> 1, wc = w & 1;

  const int t0 = tid, t1 = 256 + tid;
  const int r0 = t0 >> 2, q0 = (t0 & 3) ^ (r0 & 3);
  const int r1 = t1 >> 2, q1 = (t1 & 3) ^ (r1 & 3);
  const _Float16* gA0 = A + ((size_t)(bm * 128 + r0)) * 1024 + q0 * 8;
  const _Float16* gA1 = A + ((size_t)(bm * 128 + r1)) * 1024 + q1 * 8;
  const _Float16* gB0 = BT + ((size_t)(bn * 128 + r0)) * 1024 + q0 * 8;
  const _Float16* gB1 = BT + ((size_t)(bn * 128 + r1)) * 1024 + q1 * 8;

  const int ps = ((l >> 4) ^ (l & 3)) * 8;  // physical slot * 8
  int offA[4], offB[4];
#pragma unroll
  for (int i = 0; i < 4; ++i) {
    offA[i] = (wr * 64 + i * 16 + (l & 15)) * 32 + ps;
    offB[i] = (wc * 64 + i * 16 + (l & 15)) * 32 + ps;
  }

  f32x4 acc[4][4];
#pragma unroll
  for (int i = 0; i < 4; ++i)
#pragma unroll
    for (int j = 0; j < 4; ++j) acc[i][j] = (f32x4){0.f, 0.f, 0.f, 0.f};

  load_lds16(gA0, &ldsA[0][0] + t0 * 8);
  load_lds16(gA1, &ldsA[0][0] + t1 * 8);
  load_lds16(gB0, &ldsB[0][0] + t0 * 8);
  load_lds16(gB1, &ldsB[0][0] + t1 * 8);

  int buf = 0;
  for (int kt = 0; kt < 32; ++kt) {
    __syncthreads();
    if (kt + 1 < 32) {
      int k0 = (kt + 1) * 32;
      load_lds16(gA0 + k0, &ldsA[buf ^ 1][0] + t0 * 8);
      load_lds16(gA1 + k0, &ldsA[buf ^ 1][0] + t1 * 8);
      load_lds16(gB0 + k0, &ldsB[buf ^ 1][0] + t0 * 8);
      load_lds16(gB1 + k0, &ldsB[buf ^ 1][0] + t1 * 8);
    }
    f16x8 af[4], bf[4];
#pragma unroll
    for (int i = 0; i < 4; ++i)
      af[i] = *(const f16x8*)(&ldsA[buf][offA[i]]);
#pragma unroll
    for (int i = 0; i < 4; ++i)
      bf[i] = *(const f16x8*)(&ldsB[buf][offB[i]]);
#pragma unroll
    for (int i = 0; i < 4; ++i)
#pragma unroll
      for (int j = 0; j < 4; ++j)
        acc[i][j] = __builtin_amdgcn_mfma_f32_16x16x32_f16(af[i], bf[j],
                                                           acc[i][j], 0, 0, 0);
    buf ^= 1;
  }

#pragma unroll
  for (int i = 0; i < 4; ++i) {
    int R = bm * 128 + wr * 64 + i * 16 + (l >> 4) * 4;
#pragma unroll
    for (int j = 0; j < 4; ++j) {
      int colb = bn * 128 + wc * 64 + j * 16;
      if (colb >= FB) continue;
      int col = colb + (l & 15);
#pragma unroll
      for (int r = 0; r < 4; ++r)
        XK[(size_t)(R + r) * FB + col] = __float2half(acc[i][j][r]);
    }
  }
}

// ---------------------------------------------------------------------------
// K3: projection (unchanged).
// ---------------------------------------------------------------------------
template <int O>
__global__ __launch_bounds__(256) void k_proj(
    const float* __restrict__ X0, const __half* __restrict__ XK,
    const float* __restrict__ W, __half* __restrict__ XP) {
  const int n = blockIdx.x;
  const int s = blockIdx.y;  // 0..10
  __shared__ float srcT[FD * 36];
  __shared__ float wL[FD * O];
  const int tid = threadIdx.x;
  for (int p = tid; p < FB; p += 256) {
    int b = p / FD;
    int f = p - b * FD;
    float v = (s == 0) ? X0[(size_t)n * FB + p]
                       : __half2float(XK[((size_t)(s - 1) * NN + n) * FB + p]);
    srcT[f * 36 + b] = v;
  }
  for (int p = tid; p < FD * O; p += 256) wL[p] = W[p];
  __syncthreads();
  constexpr int OG = O / 4;
  constexpr int BG = 256 / OG;
  constexpr int BPT = 32 / BG;
  const int og = tid % OG;
  const int bg = tid / OG;
  const int o0 = og * 4;
  const int b0 = bg * BPT;
  float acc[BPT][4];
#pragma unroll
  for (int i = 0; i < BPT; ++i)
#pragma unroll
    for (int j = 0; j < 4; ++j) acc[i][j] = 0.f;
  for (int f = 0; f < FD; ++f) {
    float4 wv = *reinterpret_cast<const float4*>(&wL[f * O + o0]);
    float wa[4] = {wv.x, wv.y, wv.z, wv.w};
#pragma unroll
    for (int bb = 0; bb < BPT; ++bb) {
      float sv = srcT[f * 36 + b0 + bb];
#pragma unroll
      for (int oo = 0; oo < 4; ++oo) acc[bb][oo] += sv * wa[oo];
    }
  }
#pragma unroll
  for (int bb = 0; bb < BPT; ++bb) {
    __half2* dst = reinterpret_cast<__half2*>(
        &XP[(((size_t)s * NN + n) * BB + b0 + bb) * O + o0]);
    dst[0] = __floats2half2_rn(acc[bb][0], acc[bb][1]);
    dst[1] = __floats2half2_rn(acc[bb][2], acc[bb][3]);
  }
}

// ---------------------------------------------------------------------------
// K4: attention via MFMA.  Writes xi/xs as fp16 hi+lo into CAT2h/CAT2l
// [(n*32+b)][2*O] (xi at col 0, xs at col O).
// ---------------------------------------------------------------------------
template <int O>
__global__ __launch_bounds__(256) void k_attend_mfma(
    const __half* __restrict__ XP, const float* __restrict__ Watt,
    const float* __restrict__ Watt1, _Float16* __restrict__ CAT2h,
    _Float16* __restrict__ CAT2l) {
  constexpr int MTW = O / 64;       // q-tiles per wave (2 or 1)
  constexpr int KS = O / 32;        // k-steps (4 or 2)
  constexpr int SLOTS = O / 8;      // 16B slots per row (16 or 8)
  constexpr int SWZ = SLOTS - 1;
  constexpr int OH = O / 2;         // u32 per row
  const int n = blockIdx.x;
  const int tid = threadIdx.x;
  const int l = tid & 63;
  const int w = tid >> 6;

  __shared__ _Float16 xpL[160 * O];
  __shared__ float sPartL[4][160];
  __shared__ float aL[32][5];

  const int qbase = w * (O / 4);
  f16x8 afr[MTW][KS];
#pragma unroll
  for (int mt = 0; mt < MTW; ++mt) {
    const int q = qbase + mt * 16 + (l & 15);
#pragma unroll
    for (int ks = 0; ks < KS; ++ks) {
#pragma unroll
      for (int e = 0; e < 8; ++e) {
        int o = ks * 32 + (l >> 4) * 8 + e;
        afr[mt][ks][e] = (_Float16)Watt[((size_t)n * O + o) * O + q];
      }
    }
  }
  float wt1[MTW][4];
#pragma unroll
  for (int mt = 0; mt < MTW; ++mt)
#pragma unroll
    for (int r = 0; r < 4; ++r)
      wt1[mt][r] = Watt1[(size_t)n * O + qbase + mt * 16 + (l >> 4) * 4 + r];

  for (int g = 0; g < 2; ++g) {
    if (g) __syncthreads();
    {
      const uint32_t* xsrc = reinterpret_cast<const uint32_t*>(XP);
      uint32_t* xdst = reinterpret_cast<uint32_t*>(xpL);
      for (int p = tid; p < 160 * OH; p += 256) {
        int row = p / OH;
        int oh = p - row * OH;
        int slot = oh >> 2;
        int phys = slot ^ (row & SWZ);
        int si = row >> 5, b = row & 31;
        size_t gi = (((size_t)(1 + g * 5 + si) * NN + n) * BB + b) * OH + oh;
        xdst[row * OH + phys * 4 + (oh & 3)] = xsrc[gi];
      }
    }
    __syncthreads();

    for (int nt = 0; nt < 10; ++nt) {
      f32x4 acc[MTW];
#pragma unroll
      for (int mt = 0; mt < MTW; ++mt) acc[mt] = (f32x4){0.f, 0.f, 0.f, 0.f};
      const int row = nt * 16 + (l & 15);
#pragma unroll
      for (int ks = 0; ks < KS; ++ks) {
        int phys = (ks * 4 + (l >> 4)) ^ (row & SWZ);
        f16x8 bf = *(const f16x8*)(&xpL[row * O + phys * 8]);
#pragma unroll
        for (int mt = 0; mt < MTW; ++mt)
          acc[mt] = __builtin_amdgcn_mfma_f32_16x16x32_f16(afr[mt][ks], bf,
                                                           acc[mt], 0, 0, 0);
      }
      float sp = 0.f;
#pragma unroll
      for (int mt = 0; mt < MTW; ++mt)
#pragma unroll
        for (int r = 0; r < 4; ++r)
          sp += fmaxf(acc[mt][r], 0.f) * wt1[mt][r];
      sp += __shfl_xor(sp, 16);
      sp += __shfl_xor(sp, 32);
      if (l < 16) sPartL[w][nt * 16 + l] = sp;
    }
    __syncthreads();

    if (tid < 32) {
      const int b = tid;
      float sv[5];
#pragma unroll
      for (int k = 0; k < 5; ++k) {
        int row = k * 32 + b;
        sv[k] = sPartL[0][row] + sPartL[1][row] + sPartL[2][row] +
                sPartL[3][row];
      }
      float mx = sv[0];
#pragma unroll
      for (int k = 1; k < 5; ++k) mx = fmaxf(mx, sv[k]);
      float e[5], sum = 0.f;
#pragma unroll
      for (int k = 0; k < 5; ++k) {
        e[k] = expf(sv[k] - mx);
        sum += e[k];
      }
      float inv = 1.f / sum;
#pragma unroll
      for (int k = 0; k < 5; ++k) aL[b][k] = e[k] * inv;
    }
    __syncthreads();

    // ---- weighted sum -> CAT2 hi/lo fp16 ----
    for (int it = 0; it < SLOTS * 32 / 256; ++it) {
      int idx = it * 256 + tid;
      int b = idx & 31;
      int sc = idx >> 5;  // logical 16B slot = 8 o's
      float o8[8] = {0.f, 0.f, 0.f, 0.f, 0.f, 0.f, 0.f, 0.f};
#pragma unroll
      for (int si = 0; si < 5; ++si) {
        int row = si * 32 + b;
        int phys = sc ^ (row & SWZ);
        f16x8 xv = *(const f16x8*)(&xpL[row * O + phys * 8]);
        float a = aL[b][si];
#pragma unroll
        for (int j = 0; j < 8; ++j) o8[j] += a * (float)xv[j];
      }
      f16x8 hv, lv;
#pragma unroll
      for (int j = 0; j < 8; ++j) {
        hv[j] = (_Float16)o8[j];
        lv[j] = (_Float16)(o8[j] - (float)hv[j]);
      }
      size_t doff = ((size_t)n * 32 + b) * (2 * O) + g * O + sc * 8;
      *reinterpret_cast<f16x8*>(CAT2h + doff) = hv;
      *reinterpret_cast<f16x8*>(CAT2l + doff) = lv;
    }
  }
}

// ---------------------------------------------------------------------------
// K5: ru Wout GEMM via split-fp16 MFMA + fused sigmoid.
// A rows r=(n*32+b): [CAT2 2*O | XP(s=0) O], K=384.  acc = AhBh + AlBh + AhBl.
// 256 blocks x (128 rows x 128 cols); 4 waves 2x2 (64x64 each).
// ---------------------------------------------------------------------------
__global__ __launch_bounds__(256, 2) void k_wout_ru_mfma(
    const _Float16* __restrict__ CAT2h, const _Float16* __restrict__ CAT2l,
    const __half* __restrict__ XP, const _Float16* __restrict__ WTh,
    const _Float16* __restrict__ WTl, const float* __restrict__ bias,
    const float* __restrict__ hx, float* __restrict__ RHX,
    float* __restrict__ UBUF) {
  constexpr int KTOT = 384, KC = 8, KT = 12;  // K-chunks: 8 CAT2 + 4 XP
  __shared__ _Float16 ldsAh[2][4096];  // [buf][128 rows][32 k]
  __shared__ _Float16 ldsAl[2][4096];
  __shared__ _Float16 ldsBh[2][4096];
  __shared__ _Float16 ldsBl[2][4096];
  const int tid = threadIdx.x;
  const int blk = blockIdx.x;  // 0..255
  const int l = tid & 63;
  const int w = tid >> 6;
  const int wr = w >> 1, wc = w & 1;

  const int t0 = tid, t1 = 256 + tid;
  const int r0 = t0 >> 2, q0 = (t0 & 3) ^ (r0 & 3);
  const int r1 = t1 >> 2, q1 = (t1 & 3) ^ (r1 & 3);
  const size_t R0 = (size_t)blk * 128 + r0, R1 = (size_t)blk * 128 + r1;
  const _Float16* pA0ch = CAT2h + R0 * 256 + q0 * 8;
  const _Float16* pA1ch = CAT2h + R1 * 256 + q1 * 8;
  const _Float16* pA0cl = CAT2l + R0 * 256 + q0 * 8;
  const _Float16* pA1cl = CAT2l + R1 * 256 + q1 * 8;
  const _Float16* pA0x = (const _Float16*)XP + R0 * 128 + q0 * 8;
  const _Float16* pA1x = (const _Float16*)XP + R1 * 128 + q1 * 8;
  const _Float16* pB0h = WTh + (size_t)r0 * KTOT + q0 * 8;
  const _Float16* pB1h = WTh + (size_t)r1 * KTOT + q1 * 8;
  const _Float16* pB0l = WTl + (size_t)r0 * KTOT + q0 * 8;
  const _Float16* pB1l = WTl + (size_t)r1 * KTOT + q1 * 8;

  const int ps = ((l >> 4) ^ (l & 3)) * 8;
  int offA[4], offB[4];
#pragma unroll
  for (int i = 0; i < 4; ++i) {
    offA[i] = (wr * 64 + i * 16 + (l & 15)) * 32 + ps;
    offB[i] = (wc * 64 + i * 16 + (l & 15)) * 32 + ps;
  }

  f32x4 acc[4][4];
#pragma unroll
  for (int i = 0; i < 4; ++i)
#pragma unroll
    for (int j = 0; j < 4; ++j) acc[i][j] = (f32x4){0.f, 0.f, 0.f, 0.f};

  // prologue: stage kt=0 (CAT2 source)
  load_lds16(pA0ch, &ldsAh[0][0] + t0 * 8);
  load_lds16(pA1ch, &ldsAh[0][0] + t1 * 8);
  load_lds16(pA0cl, &ldsAl[0][0] + t0 * 8);
  load_lds16(pA1cl, &ldsAl[0][0] + t1 * 8);
  load_lds16(pB0h, &ldsBh[0][0] + t0 * 8);
  load_lds16(pB1h, &ldsBh[0][0] + t1 * 8);
  load_lds16(pB0l, &ldsBl[0][0] + t0 * 8);
  load_lds16(pB1l, &ldsBl[0][0] + t1 * 8);

  int buf = 0;
  for (int kt = 0; kt < KT; ++kt) {
    __syncthreads();
    if (kt + 1 < KT) {
      int k1 = kt + 1;
      const _Float16* a0 =
          (k1 < KC) ? pA0ch + k1 * 32 : pA0x + (k1 - KC) * 32;
      const _Float16* a1 =
          (k1 < KC) ? pA1ch + k1 * 32 : pA1x + (k1 - KC) * 32;
      load_lds16(a0, &ldsAh[buf ^ 1][0] + t0 * 8);
      load_lds16(a1, &ldsAh[buf ^ 1][0] + t1 * 8);
      if (k1 < KC) {
        load_lds16(pA0cl + k1 * 32, &ldsAl[buf ^ 1][0] + t0 * 8);
        load_lds16(pA1cl + k1 * 32, &ldsAl[buf ^ 1][0] + t1 * 8);
      }
      load_lds16(pB0h + k1 * 32, &ldsBh[buf ^ 1][0] + t0 * 8);
      load_lds16(pB1h + k1 * 32, &ldsBh[buf ^ 1][0] + t1 * 8);
      load_lds16(pB0l + k1 * 32, &ldsBl[buf ^ 1][0] + t0 * 8);
      load_lds16(pB1l + k1 * 32, &ldsBl[buf ^ 1][0] + t1 * 8);
    }
    f16x8 ah[4], bh[4], bl[4];
#pragma unroll
    for (int i = 0; i < 4; ++i) ah[i] = *(const f16x8*)(&ldsAh[buf][offA[i]]);
#pragma unroll
    for (int i = 0; i < 4; ++i) bh[i] = *(const f16x8*)(&ldsBh[buf][offB[i]]);
#pragma unroll
    for (int i = 0; i < 4; ++i) bl[i] = *(const f16x8*)(&ldsBl[buf][offB[i]]);
#pragma unroll
    for (int i = 0; i < 4; ++i)
#pragma unroll
      for (int j = 0; j < 4; ++j) {
        acc[i][j] = __builtin_amdgcn_mfma_f32_16x16x32_f16(ah[i], bh[j],
                                                           acc[i][j], 0, 0, 0);
        acc[i][j] = __builtin_amdgcn_mfma_f32_16x16x32_f16(ah[i], bl[j],
                                                           acc[i][j], 0, 0, 0);
      }
    if (kt < KC) {
      f16x8 al[4];
#pragma unroll
      for (int i = 0; i < 4; ++i)
        al[i] = *(const f16x8*)(&ldsAl[buf][offA[i]]);
#pragma unroll
      for (int i = 0; i < 4; ++i)
#pragma unroll
        for (int j = 0; j < 4; ++j)
          acc[i][j] = __builtin_amdgcn_mfma_f32_16x16x32_f16(al[i], bh[j],
                                                             acc[i][j], 0, 0, 0);
    }
    buf ^= 1;
  }

#pragma unroll
  for (int i = 0; i < 4; ++i) {
    int R = blk * 128 + wr * 64 + i * 16 + (l >> 4) * 4;
#pragma unroll
    for (int j = 0; j < 4; ++j) {
      int o = wc * 64 + j * 16 + (l & 15);
      float bv = bias[o];
#pragma unroll
      for (int rr = 0; rr < 4; ++rr) {
        int Rr = R + rr;
        int n = Rr >> 5, b = Rr & 31;
        size_t base = ((size_t)b * NN + n) * 64;
        float val = 1.f / (1.f + expf(-(acc[i][j][rr] + bv)));
        if (o < 64)
          RHX[base + o] = val * hx[base + o];
        else
          UBUF[base + (o - 64)] = val;
      }
    }
  }
}

// ---------------------------------------------------------------------------
// K6: candidate Wout GEMM via split-fp16 MFMA + fused tanh + gate -> out.
// K=192 (4 CAT2 chunks + 2 XP chunks).  256 blocks x (128 rows x 64 cols);
// 4 waves, each 32 rows x 64 cols (acc 2x4).
// ---------------------------------------------------------------------------
__global__ __launch_bounds__(256, 2) void k_wout_c_mfma(
    const _Float16* __restrict__ CAT2h, const _Float16* __restrict__ CAT2l,
    const __half* __restrict__ XP, const _Float16* __restrict__ WTh,
    const _Float16* __restrict__ WTl, const float* __restrict__ bias,
    const float* __restrict__ UBUF, const float* __restrict__ hx,
    float* __restrict__ out) {
  constexpr int KTOT = 192, KC = 4, KT = 6;
  __shared__ _Float16 ldsAh[2][4096];  // [buf][128 rows][32 k]
  __shared__ _Float16 ldsAl[2][4096];
  __shared__ _Float16 ldsBh[2][2048];  // [buf][64 rows][32 k]
  __shared__ _Float16 ldsBl[2][2048];
  const int tid = threadIdx.x;
  const int blk = blockIdx.x;  // 0..255
  const int l = tid & 63;
  const int w = tid >> 6;

  const int t0 = tid, t1 = 256 + tid;
  const int r0 = t0 >> 2, q0 = (t0 & 3) ^ (r0 & 3);
  const int r1 = t1 >> 2, q1 = (t1 & 3) ^ (r1 & 3);
  const size_t R0 = (size_t)blk * 128 + r0, R1 = (size_t)blk * 128 + r1;
  const _Float16* pA0ch = CAT2h + R0 * 128 + q0 * 8;
  const _Float16* pA1ch = CAT2h + R1 * 128 + q1 * 8;
  const _Float16* pA0cl = CAT2l + R0 * 128 + q0 * 8;
  const _Float16* pA1cl = CAT2l + R1 * 128 + q1 * 8;
  const _Float16* pA0x = (const _Float16*)XP + R0 * 64 + q0 * 8;
  const _Float16* pA1x = (const _Float16*)XP + R1 * 64 + q1 * 8;
  const int rb = tid >> 2, qb = (tid & 3) ^ (rb & 3);
  const _Float16* pBh = WTh + (size_t)rb * KTOT + qb * 8;
  const _Float16* pBl = WTl + (size_t)rb * KTOT + qb * 8;

  const int ps = ((l >> 4) ^ (l & 3)) * 8;
  int offA[2], offB[4];
#pragma unroll
  for (int i = 0; i < 2; ++i)
    offA[i] = (w * 32 + i * 16 + (l & 15)) * 32 + ps;
#pragma unroll
  for (int j = 0; j < 4; ++j) offB[j] = (j * 16 + (l & 15)) * 32 + ps;

  f32x4 acc[2][4];
#pragma unroll
  for (int i = 0; i < 2; ++i)
#pragma unroll
    for (int j = 0; j < 4; ++j) acc[i][j] = (f32x4){0.f, 0.f, 0.f, 0.f};

  load_lds16(pA0ch, &ldsAh[0][0] + t0 * 8);
  load_lds16(pA1ch, &ldsAh[0][0] + t1 * 8);
  load_lds16(pA0cl, &ldsAl[0][0] + t0 * 8);
  load_lds16(pA1cl, &ldsAl[0][0] + t1 * 8);
  load_lds16(pBh, &ldsBh[0][0] + tid * 8);
  load_lds16(pBl, &ldsBl[0][0] + tid * 8);

  int buf = 0;
  for (int kt = 0; kt < KT; ++kt) {
    __syncthreads();
    if (kt + 1 < KT) {
      int k1 = kt + 1;
      const _Float16* a0 =
          (k1 < KC) ? pA0ch + k1 * 32 : pA0x + (k1 - KC) * 32;
      const _Float16* a1 =
          (k1 < KC) ? pA1ch + k1 * 32 : pA1x + (k1 - KC) * 32;
      load_lds16(a0, &ldsAh[buf ^ 1][0] + t0 * 8);
      load_lds16(a1, &ldsAh[buf ^ 1][0] + t1 * 8);
      if (k1 < KC) {
        load_lds16(pA0cl + k1 * 32, &ldsAl[buf ^ 1][0] + t0 * 8);
        load_lds16(pA1cl + k1 * 32, &ldsAl[buf ^ 1][0] + t1 * 8);
      }
      load_lds16(pBh + k1 * 32, &ldsBh[buf ^ 1][0] + tid * 8);
      load_lds16(pBl + k1 * 32, &ldsBl[buf ^ 1][0] + tid * 8);
    }
    f16x8 ah[2], bh[4], bl[4];
#pragma unroll
    for (int i = 0; i < 2; ++i) ah[i] = *(const f16x8*)(&ldsAh[buf][offA[i]]);
#pragma unroll
    for (int j = 0; j < 4; ++j) bh[j] = *(const f16x8*)(&ldsBh[buf][offB[j]]);
#pragma unroll
    for (int j = 0; j < 4; ++j) bl[j] = *(const f16x8*)(&ldsBl[buf][offB[j]]);
#pragma unroll
    for (int i = 0; i < 2; ++i)
#pragma unroll
      for (int j = 0; j < 4; ++j) {
        acc[i][j] = __builtin_amdgcn_mfma_f32_16x16x32_f16(ah[i], bh[j],
                                                           acc[i][j], 0, 0, 0);
        acc[i][j] = __builtin_amdgcn_mfma_f32_16x16x32_f16(ah[i], bl[j],
                                                           acc[i][j], 0, 0, 0);
      }
    if (kt < KC) {
      f16x8 al[2];
#pragma unroll
      for (int i = 0; i < 2; ++i)
        al[i] = *(const f16x8*)(&ldsAl[buf][offA[i]]);
#pragma unroll
      for (int i = 0; i < 2; ++i)
#pragma unroll
        for (int j = 0; j < 4; ++j)
          acc[i][j] = __builtin_amdgcn_mfma_f32_16x16x32_f16(al[i], bh[j],
                                                             acc[i][j], 0, 0, 0);
    }
    buf ^= 1;
  }

#pragma unroll
  for (int i = 0; i < 2; ++i) {
    int R = blk * 128 + w * 32 + i * 16 + (l >> 4) * 4;
#pragma unroll
    for (int j = 0; j < 4; ++j) {
      int o = j * 16 + (l & 15);
      float bv = bias[o];
#pragma unroll
      for (int rr = 0; rr < 4; ++rr) {
        int Rr = R + rr;
        int n = Rr >> 5, b = Rr & 31;
        size_t idx = ((size_t)b * NN + n) * 64 + o;
        float cval = tanhf(acc[i][j][rr] + bv);
        float u = UBUF[idx];
        out[idx] = u * hx[idx] + (1.f - u) * cval;
      }
    }
  }
}

// ---------------------------------------------------------------------------
extern "C" void kernel_launch(void* const* d_in, const int* in_sizes, int n_in,
                              void* d_out, int out_size, void* d_ws,
                              size_t ws_size, hipStream_t stream) {
  const float* inputs   = (const float*)d_in[0];
  const float* hx       = (const float*)d_in[1];
  const float* adj      = (const float*)d_in[2];
  const float* mask     = (const float*)d_in[3];
  const float* W_ru     = (const float*)d_in[4];
  const float* Watt_ru  = (const float*)d_in[5];
  const float* Watt1_ru = (const float*)d_in[6];
  const float* Wout_ru  = (const float*)d_in[7];
  const float* b_ru     = (const float*)d_in[8];
  const float* W_c      = (const float*)d_in[9];
  const float* Watt_c   = (const float*)d_in[10];
  const float* Watt1_c  = (const float*)d_in[11];
  const float* Wout_c   = (const float*)d_in[12];
  const float* b_c      = (const float*)d_in[13];

  // workspace arena (~186.7 MB):
  //   X0     fp32 [1024][2112]         @ 0           (8,650,752)
  //   XK     fp16 [10][1024][2112]     @ 8,650,752   (43,253,760)
  //     CAT2h fp16 [32768][256] aliases XK @ 8,650,752  (16,777,216)
  //     CAT2l fp16 [32768][256]           @ 25,427,968 (16,777,216)
  //   XP     fp16 [11][1024][32][O]    @ 51,904,512  (92,274,688 max)
  //   RHX    fp32                      @ 144,179,200 (8,388,608)
  //   UBUF   fp32                      @ 152,567,808 (8,388,608)
  //   A_all  fp16 [10][1024][1024]     @ 160,956,416 (20,971,520)
  //   X0T    fp16 [2176][1024]         @ 181,927,936 (4,456,448)
  //   WThru  fp16 [128][384]           @ 186,384,384 (98,304)
  //   WTlru  fp16 [128][384]           @ 186,482,688 (98,304)
  //   WThc   fp16 [64][192]            @ 186,580,992 (24,576)
  //   WTlc   fp16 [64][192]            @ 186,605,568 (24,576) end 186,630,144
  char* ws = (char*)d_ws;
  float*     X0    = (float*)(ws);
  __half*    XK    = (__half*)(ws + 8650752);
  _Float16*  CAT2h = (_Float16*)(ws + 8650752);
  _Float16*  CAT2l = (_Float16*)(ws + 25427968);
  __half*    XP    = (__half*)(ws + 51904512);
  float*     RHX   = (float*)(ws + 144179200);
  float*     UBUF  = (float*)(ws + 152567808);
  _Float16*  A_all = (_Float16*)(ws + 160956416);
  _Float16*  X0T   = (_Float16*)(ws + 181927936);
  _Float16*  WThru = (_Float16*)(ws + 186384384);
  _Float16*  WTlru = (_Float16*)(ws + 186482688);
  _Float16*  WThc  = (_Float16*)(ws + 186580992);
  _Float16*  WTlc  = (_Float16*)(ws + 186605568);
  float*     out   = (float*)d_out;

  k_build_amats<<<1024, 256, 0, stream>>>(adj, mask, A_all);
  k_prep_wout<<<240, 256, 0, stream>>>(Wout_ru, Wout_c, WThru, WTlru, WThc,
                                       WTlc);

  // ---- gate gconv (O = 2U = 128) ----
  k_build_x0<<<8448, 256, 0, stream>>>(inputs, hx, X0);
  k_build_x0t<<<dim3(32, 16), 256, 0, stream>>>(inputs, hx, X0T);
  k_supports_mfma<<<dim3(17, 80), 256, 0, stream>>>(A_all, X0T, XK);
  k_proj<128><<<dim3(1024, 11), 256, 0, stream>>>(X0, XK, W_ru, XP);
  k_attend_mfma<128><<<1024, 256, 0, stream>>>(XP, Watt_ru, Watt1_ru, CAT2h,
                                               CAT2l);
  k_wout_ru_mfma<<<256, 256, 0, stream>>>(CAT2h, CAT2l, XP, WThru, WTlru, b_ru,
                                          hx, RHX, UBUF);
  // ---- candidate gconv (O = U = 64), state = r*hx ----
  k_build_x0<<<8448, 256, 0, stream>>>(inputs, RHX, X0);
  k_build_x0t<<<dim3(32, 16), 256, 0, stream>>>(inputs, RHX, X0T);
  k_supports_mfma<<<dim3(17, 80), 256, 0, stream>>>(A_all, X0T, XK);
  k_proj<64><<<dim3(1024, 11), 256, 0, stream>>>(X0, XK, W_c, XP);
  k_attend_mfma<64><<<1024, 256, 0, stream>>>(XP, Watt_c, Watt1_c, CAT2h,
                                              CAT2l);
  k_wout_c_mfma<<<256, 256, 0, stream>>>(CAT2h, CAT2l, XP, WThc, WTlc, b_c,
                                         UBUF, hx, out);
}

// Round 6
// 344.539 us; speedup vs baseline: 10.0096x; 1.3960x over previous
//
#include <hip/hip_runtime.h>
#include <hip/hip_fp16.h>
#include <cstdint>
#include <cstddef>

#define NN 1024   // nodes
#define BB 32     // batch

typedef _Float16 f16x8 __attribute__((ext_vector_type(8)));
typedef _Float16 f16x4 __attribute__((ext_vector_type(4)));
typedef float f32x4 __attribute__((ext_vector_type(4)));

__device__ __forceinline__ void load_lds16(const void* g, void* l) {
  __builtin_amdgcn_global_load_lds(
      (const __attribute__((address_space(1))) void*)g,
      (__attribute__((address_space(3))) void*)l, 16, 0, 0);
}

// ---------------------------------------------------------------------------
// K0: build the 10 support matrices (shared by both gconvs), fp16.
// ---------------------------------------------------------------------------
__global__ __launch_bounds__(256) void k_build_amats(
    const float* __restrict__ adj, const float* __restrict__ mask,
    _Float16* __restrict__ A) {
  int q = blockIdx.x * 256 + threadIdx.x;  // 0..262143 quads
  int i = q >> 8;
  int j0 = (q & 255) << 2;
  size_t off = (size_t)i * 1024 + j0;
  float4 a0 = *(const float4*)(adj + off);
  float4 a1 = *(const float4*)(adj + (1u << 20) + off);
  f16x4 r;
  r[0] = a0.x; r[1] = a0.y; r[2] = a0.z; r[3] = a0.w;
  *(f16x4*)(A + off) = r;
  r[0] = a1.x; r[1] = a1.y; r[2] = a1.z; r[3] = a1.w;
  *(f16x4*)(A + (size_t)9 * 1048576 + off) = r;
#pragma unroll
  for (int l = 0; l < 8; ++l) {
    float4 mk = *(const float4*)(mask + (size_t)l * 1048576 + off);
    float4 base = (l < 4) ? a0 : a1;
    r[0] = mk.x * base.x; r[1] = mk.y * base.y;
    r[2] = mk.z * base.z; r[3] = mk.w * base.w;
    *(f16x4*)(A + (size_t)(l + 1) * 1048576 + off) = r;
  }
}

// ---------------------------------------------------------------------------
// K0b: transpose+convert Wout matrices to fp16 hi/lo [O][K]
// ---------------------------------------------------------------------------
__global__ __launch_bounds__(256) void k_prep_wout(
    const float* __restrict__ Wru, const float* __restrict__ Wc,
    _Float16* __restrict__ WThru, _Float16* __restrict__ WTlru,
    _Float16* __restrict__ WThc, _Float16* __restrict__ WTlc) {
  int id = blockIdx.x * 256 + threadIdx.x;
  if (id < 128 * 384) {
    int o = id & 127, k = id >> 7;
    float w = Wru[k * 128 + o];
    _Float16 h = (_Float16)w;
    WThru[o * 384 + k] = h;
    WTlru[o * 384 + k] = (_Float16)(w - (float)h);
  } else {
    int id2 = id - 128 * 384;
    if (id2 < 64 * 192) {
      int o = id2 & 63, k = id2 >> 6;
      float w = Wc[k * 64 + o];
      _Float16 h = (_Float16)w;
      WThc[o * 192 + k] = h;
      WTlc[o * 192 + k] = (_Float16)(w - (float)h);
    }
  }
}

// ---------------------------------------------------------------------------
// K1: build X0P fp16 [(b*1024+j)][96]: f<2 inputs, f-2<64 state, pad 0.
// ---------------------------------------------------------------------------
__global__ __launch_bounds__(256) void k_build_x0p(
    const float* __restrict__ inp, const float* __restrict__ state,
    _Float16* __restrict__ X0P) {
  const int b = blockIdx.x;        // 0..31
  const int j0 = blockIdx.y * 64;  // 0..960
  const int tid = threadIdx.x;
  for (int p = tid; p < 4096; p += 256) {
    int jj = p >> 6, f = p & 63;
    X0P[((size_t)(b * 1024 + j0 + jj)) * 96 + 2 + f] =
        (_Float16)state[(size_t)b * 65536 + (j0 + jj) * 64 + f];
  }
  if (tid < 128) {
    int jj = tid >> 1, f = tid & 1;
    X0P[((size_t)(b * 1024 + j0 + jj)) * 96 + f] =
        (_Float16)inp[(size_t)b * 2048 + (j0 + jj) * 2 + f];
    X0P[((size_t)(b * 1024 + j0 + 32 + jj)) * 96 + f] =
        (_Float16)inp[(size_t)b * 2048 + (j0 + 32 + jj) * 2 + f];
  }
  for (int p = tid; p < 64 * 32; p += 256) {
    int jj = p >> 5, f = 66 + (p & 31);
    if (f < 96)
      X0P[((size_t)(b * 1024 + j0 + jj)) * 96 + f] = (_Float16)0.f;
  }
}

// ---------------------------------------------------------------------------
// K2: proj0 GEMM via MFMA.  XP0[(j,b)][o] = sum_f x[b,j,f] * W[f,o]
//   A = W^T [O x 96] (frags from global, zero-padded f>=66),
//   B^T = X0P rows (b*1024+j) x 96.  Also writes XP0T[(b*O+o)][j].
// ---------------------------------------------------------------------------
template <int O>
__global__ __launch_bounds__(256, 2) void k_proj0_mfma(
    const _Float16* __restrict__ X0P, const float* __restrict__ W,
    _Float16* __restrict__ XP0, _Float16* __restrict__ XP0T) {
  constexpr int WR = O / 64;      // 2 for O=128, 1 for O=64
  constexpr int WC = 4 / WR;      // 2 or 4
  constexpr int TN = WC * 64;     // 128 or 256
  constexpr int NPT = TN / 64;    // staging chunks per thread (2 or 4)
  __shared__ _Float16 ldsB[2][TN * 32];
  const int tid = threadIdx.x;
  const int c0 = blockIdx.x * TN;  // global col base (b*1024+j), within one b
  const int b = c0 >> 10;
  const int l = tid & 63;
  const int w = tid >> 6;
  const int wr = w / WC, wc = w % WC;

  // A-frags (W^T) in registers, zero-padded
  f16x8 af[4][3];
#pragma unroll
  for (int i = 0; i < 4; ++i) {
    int o = wr * 64 + i * 16 + (l & 15);
#pragma unroll
    for (int ks = 0; ks < 3; ++ks) {
#pragma unroll
      for (int e = 0; e < 8; ++e) {
        int f = ks * 32 + (l >> 4) * 8 + e;
        af[i][ks][e] = (f < 66) ? (_Float16)W[f * O + o] : (_Float16)0.f;
      }
    }
  }

  int tt[NPT], rr[NPT], qq[NPT];
#pragma unroll
  for (int u = 0; u < NPT; ++u) {
    tt[u] = u * 256 + tid;
    rr[u] = tt[u] >> 2;
    qq[u] = (tt[u] & 3) ^ (rr[u] & 3);
  }

  const int ps = ((l >> 4) ^ (l & 3)) * 8;
  int offB[4];
#pragma unroll
  for (int j = 0; j < 4; ++j)
    offB[j] = (wc * 64 + j * 16 + (l & 15)) * 32 + ps;

  f32x4 acc[4][4];
#pragma unroll
  for (int i = 0; i < 4; ++i)
#pragma unroll
    for (int j = 0; j < 4; ++j) acc[i][j] = (f32x4){0.f, 0.f, 0.f, 0.f};

#pragma unroll
  for (int u = 0; u < NPT; ++u)
    load_lds16(X0P + (size_t)(c0 + rr[u]) * 96 + qq[u] * 8,
               &ldsB[0][0] + tt[u] * 8);

  int buf = 0;
  for (int kt = 0; kt < 3; ++kt) {
    __syncthreads();
    if (kt + 1 < 3) {
#pragma unroll
      for (int u = 0; u < NPT; ++u)
        load_lds16(X0P + (size_t)(c0 + rr[u]) * 96 + (kt + 1) * 32 + qq[u] * 8,
                   &ldsB[buf ^ 1][0] + tt[u] * 8);
    }
    f16x8 bf[4];
#pragma unroll
    for (int j = 0; j < 4; ++j) bf[j] = *(const f16x8*)(&ldsB[buf][offB[j]]);
#pragma unroll
    for (int i = 0; i < 4; ++i)
#pragma unroll
      for (int j = 0; j < 4; ++j)
        acc[i][j] = __builtin_amdgcn_mfma_f32_16x16x32_f16(af[i][kt], bf[j],
                                                           acc[i][j], 0, 0, 0);
    buf ^= 1;
  }

#pragma unroll
  for (int i = 0; i < 4; ++i) {
    int ob = wr * 64 + i * 16 + (l >> 4) * 4;  // 4 consecutive o
#pragma unroll
    for (int j = 0; j < 4; ++j) {
      int jn = (c0 & 1023) + wc * 64 + j * 16 + (l & 15);
      f16x4 hv;
#pragma unroll
      for (int r = 0; r < 4; ++r) {
        hv[r] = (_Float16)acc[i][j][r];
        XP0T[((size_t)b * O + ob + r) * 1024 + jn] = hv[r];
      }
      *(f16x4*)(XP0 + ((size_t)jn * 32 + b) * O + ob) = hv;
    }
  }
}

// ---------------------------------------------------------------------------
// K3: supports GEMM on projected tensor.
// XPD[(m*1024+i)][c] = sum_j A_m[i][j] * XP0[(j,b)][o],  c = b*O+o, CN=32*O.
// B^T = XP0T rows (c) x 1024.  128x128 tile, BK=32, 4 waves 2x2.
// ---------------------------------------------------------------------------
template <int CN>
__global__ __launch_bounds__(256, 2) void k_supports2_mfma(
    const _Float16* __restrict__ A, const _Float16* __restrict__ BT,
    _Float16* __restrict__ XPD) {
  __shared__ _Float16 ldsA[2][4096];  // [buf][128 rows][32 k]
  __shared__ _Float16 ldsB[2][4096];
  const int tid = threadIdx.x;
  const int bn = blockIdx.x;  // col tiles (CN/128)
  const int bm = blockIdx.y;  // 0..79
  const int l = tid & 63;
  const int w = tid >> 6;
  const int wr = w >> 1, wc = w & 1;

  const int t0 = tid, t1 = 256 + tid;
  const int r0 = t0 >> 2, q0 = (t0 & 3) ^ (r0 & 3);
  const int r1 = t1 >> 2, q1 = (t1 & 3) ^ (r1 & 3);
  const _Float16* gA0 = A + ((size_t)(bm * 128 + r0)) * 1024 + q0 * 8;
  const _Float16* gA1 = A + ((size_t)(bm * 128 + r1)) * 1024 + q1 * 8;
  const _Float16* gB0 = BT + ((size_t)(bn * 128 + r0)) * 1024 + q0 * 8;
  const _Float16* gB1 = BT + ((size_t)(bn * 128 + r1)) * 1024 + q1 * 8;

  const int ps = ((l >> 4) ^ (l & 3)) * 8;
  int offA[4], offB[4];
#pragma unroll
  for (int i = 0; i < 4; ++i) {
    offA[i] = (wr * 64 + i * 16 + (l & 15)) * 32 + ps;
    offB[i] = (wc * 64 + i * 16 + (l & 15)) * 32 + ps;
  }

  f32x4 acc[4][4];
#pragma unroll
  for (int i = 0; i < 4; ++i)
#pragma unroll
    for (int j = 0; j < 4; ++j) acc[i][j] = (f32x4){0.f, 0.f, 0.f, 0.f};

  load_lds16(gA0, &ldsA[0][0] + t0 * 8);
  load_lds16(gA1, &ldsA[0][0] + t1 * 8);
  load_lds16(gB0, &ldsB[0][0] + t0 * 8);
  load_lds16(gB1, &ldsB[0][0] + t1 * 8);

  int buf = 0;
  for (int kt = 0; kt < 32; ++kt) {
    __syncthreads();
    if (kt + 1 < 32) {
      int k0 = (kt + 1) * 32;
      load_lds16(gA0 + k0, &ldsA[buf ^ 1][0] + t0 * 8);
      load_lds16(gA1 + k0, &ldsA[buf ^ 1][0] + t1 * 8);
      load_lds16(gB0 + k0, &ldsB[buf ^ 1][0] + t0 * 8);
      load_lds16(gB1 + k0, &ldsB[buf ^ 1][0] + t1 * 8);
    }
    f16x8 af[4], bf[4];
#pragma unroll
    for (int i = 0; i < 4; ++i)
      af[i] = *(const f16x8*)(&ldsA[buf][offA[i]]);
#pragma unroll
    for (int i = 0; i < 4; ++i)
      bf[i] = *(const f16x8*)(&ldsB[buf][offB[i]]);
#pragma unroll
    for (int i = 0; i < 4; ++i)
#pragma unroll
      for (int j = 0; j < 4; ++j)
        acc[i][j] = __builtin_amdgcn_mfma_f32_16x16x32_f16(af[i], bf[j],
                                                           acc[i][j], 0, 0, 0);
    buf ^= 1;
  }

#pragma unroll
  for (int i = 0; i < 4; ++i) {
    int R = bm * 128 + wr * 64 + i * 16 + (l >> 4) * 4;
#pragma unroll
    for (int j = 0; j < 4; ++j) {
      int col = bn * 128 + wc * 64 + j * 16 + (l & 15);
#pragma unroll
      for (int r = 0; r < 4; ++r)
        XPD[(size_t)(R + r) * CN + col] = (_Float16)acc[i][j][r];
    }
  }
}

// ---------------------------------------------------------------------------
// K4: attention via MFMA (reads XPD rows [(s'*1024+n)][CN], s'=g*5+si).
// Writes xi/xs as fp16 hi+lo into CAT2h/CAT2l [(n*32+b)][2*O].
// ---------------------------------------------------------------------------
template <int O>
__global__ __launch_bounds__(256) void k_attend_mfma(
    const __half* __restrict__ XPD, const float* __restrict__ Watt,
    const float* __restrict__ Watt1, _Float16* __restrict__ CAT2h,
    _Float16* __restrict__ CAT2l) {
  constexpr int MTW = O / 64;       // q-tiles per wave (2 or 1)
  constexpr int KS = O / 32;        // k-steps (4 or 2)
  constexpr int SLOTS = O / 8;      // 16B slots per row (16 or 8)
  constexpr int SWZ = SLOTS - 1;
  constexpr int OH = O / 2;         // u32 per (b) slice
  const int n = blockIdx.x;
  const int tid = threadIdx.x;
  const int l = tid & 63;
  const int w = tid >> 6;

  __shared__ _Float16 xpL[160 * O];
  __shared__ float sPartL[4][160];
  __shared__ float aL[32][5];

  const int qbase = w * (O / 4);
  f16x8 afr[MTW][KS];
#pragma unroll
  for (int mt = 0; mt < MTW; ++mt) {
    const int q = qbase + mt * 16 + (l & 15);
#pragma unroll
    for (int ks = 0; ks < KS; ++ks) {
#pragma unroll
      for (int e = 0; e < 8; ++e) {
        int o = ks * 32 + (l >> 4) * 8 + e;
        afr[mt][ks][e] = (_Float16)Watt[((size_t)n * O + o) * O + q];
      }
    }
  }
  float wt1[MTW][4];
#pragma unroll
  for (int mt = 0; mt < MTW; ++mt)
#pragma unroll
    for (int r = 0; r < 4; ++r)
      wt1[mt][r] = Watt1[(size_t)n * O + qbase + mt * 16 + (l >> 4) * 4 + r];

  for (int g = 0; g < 2; ++g) {
    if (g) __syncthreads();
    {
      const uint32_t* xsrc = reinterpret_cast<const uint32_t*>(XPD);
      uint32_t* xdst = reinterpret_cast<uint32_t*>(xpL);
      for (int p = tid; p < 160 * OH; p += 256) {
        int row = p / OH;
        int oh = p - row * OH;
        int slot = oh >> 2;
        int phys = slot ^ (row & SWZ);
        int si = row >> 5, b = row & 31;
        size_t gi = ((size_t)(g * 5 + si) * 1024 + n) * (size_t)(16 * O) +
                    b * OH + oh;
        xdst[row * OH + phys * 4 + (oh & 3)] = xsrc[gi];
      }
    }
    __syncthreads();

    for (int nt = 0; nt < 10; ++nt) {
      f32x4 acc[MTW];
#pragma unroll
      for (int mt = 0; mt < MTW; ++mt) acc[mt] = (f32x4){0.f, 0.f, 0.f, 0.f};
      const int row = nt * 16 + (l & 15);
#pragma unroll
      for (int ks = 0; ks < KS; ++ks) {
        int phys = (ks * 4 + (l >> 4)) ^ (row & SWZ);
        f16x8 bf = *(const f16x8*)(&xpL[row * O + phys * 8]);
#pragma unroll
        for (int mt = 0; mt < MTW; ++mt)
          acc[mt] = __builtin_amdgcn_mfma_f32_16x16x32_f16(afr[mt][ks], bf,
                                                           acc[mt], 0, 0, 0);
      }
      float sp = 0.f;
#pragma unroll
      for (int mt = 0; mt < MTW; ++mt)
#pragma unroll
        for (int r = 0; r < 4; ++r)
          sp += fmaxf(acc[mt][r], 0.f) * wt1[mt][r];
      sp += __shfl_xor(sp, 16);
      sp += __shfl_xor(sp, 32);
      if (l < 16) sPartL[w][nt * 16 + l] = sp;
    }
    __syncthreads();

    if (tid < 32) {
      const int b = tid;
      float sv[5];
#pragma unroll
      for (int k = 0; k < 5; ++k) {
        int row = k * 32 + b;
        sv[k] = sPartL[0][row] + sPartL[1][row] + sPartL[2][row] +
                sPartL[3][row];
      }
      float mx = sv[0];
#pragma unroll
      for (int k = 1; k < 5; ++k) mx = fmaxf(mx, sv[k]);
      float e[5], sum = 0.f;
#pragma unroll
      for (int k = 0; k < 5; ++k) {
        e[k] = expf(sv[k] - mx);
        sum += e[k];
      }
      float inv = 1.f / sum;
#pragma unroll
      for (int k = 0; k < 5; ++k) aL[b][k] = e[k] * inv;
    }
    __syncthreads();

    for (int it = 0; it < SLOTS * 32 / 256; ++it) {
      int idx = it * 256 + tid;
      int b = idx & 31;
      int sc = idx >> 5;
      float o8[8] = {0.f, 0.f, 0.f, 0.f, 0.f, 0.f, 0.f, 0.f};
#pragma unroll
      for (int si = 0; si < 5; ++si) {
        int row = si * 32 + b;
        int phys = sc ^ (row & SWZ);
        f16x8 xv = *(const f16x8*)(&xpL[row * O + phys * 8]);
        float a = aL[b][si];
#pragma unroll
        for (int j = 0; j < 8; ++j) o8[j] += a * (float)xv[j];
      }
      f16x8 hv, lv;
#pragma unroll
      for (int j = 0; j < 8; ++j) {
        hv[j] = (_Float16)o8[j];
        lv[j] = (_Float16)(o8[j] - (float)hv[j]);
      }
      size_t doff = ((size_t)n * 32 + b) * (2 * O) + g * O + sc * 8;
      *reinterpret_cast<f16x8*>(CAT2h + doff) = hv;
      *reinterpret_cast<f16x8*>(CAT2l + doff) = lv;
    }
  }
}

// ---------------------------------------------------------------------------
// K5: ru Wout GEMM via split-fp16 MFMA + fused sigmoid.
// ---------------------------------------------------------------------------
__global__ __launch_bounds__(256, 2) void k_wout_ru_mfma(
    const _Float16* __restrict__ CAT2h, const _Float16* __restrict__ CAT2l,
    const _Float16* __restrict__ XP0, const _Float16* __restrict__ WTh,
    const _Float16* __restrict__ WTl, const float* __restrict__ bias,
    const float* __restrict__ hx, float* __restrict__ RHX,
    float* __restrict__ UBUF) {
  constexpr int KTOT = 384, KC = 8, KT = 12;
  __shared__ _Float16 ldsAh[2][4096];
  __shared__ _Float16 ldsAl[2][4096];
  __shared__ _Float16 ldsBh[2][4096];
  __shared__ _Float16 ldsBl[2][4096];
  const int tid = threadIdx.x;
  const int blk = blockIdx.x;
  const int l = tid & 63;
  const int w = tid >> 6;
  const int wr = w >> 1, wc = w & 1;

  const int t0 = tid, t1 = 256 + tid;
  const int r0 = t0 >> 2, q0 = (t0 & 3) ^ (r0 & 3);
  const int r1 = t1 >> 2, q1 = (t1 & 3) ^ (r1 & 3);
  const size_t R0 = (size_t)blk * 128 + r0, R1 = (size_t)blk * 128 + r1;
  const _Float16* pA0ch = CAT2h + R0 * 256 + q0 * 8;
  const _Float16* pA1ch = CAT2h + R1 * 256 + q1 * 8;
  const _Float16* pA0cl = CAT2l + R0 * 256 + q0 * 8;
  const _Float16* pA1cl = CAT2l + R1 * 256 + q1 * 8;
  const _Float16* pA0x = XP0 + R0 * 128 + q0 * 8;
  const _Float16* pA1x = XP0 + R1 * 128 + q1 * 8;
  const _Float16* pB0h = WTh + (size_t)r0 * KTOT + q0 * 8;
  const _Float16* pB1h = WTh + (size_t)r1 * KTOT + q1 * 8;
  const _Float16* pB0l = WTl + (size_t)r0 * KTOT + q0 * 8;
  const _Float16* pB1l = WTl + (size_t)r1 * KTOT + q1 * 8;

  const int ps = ((l >> 4) ^ (l & 3)) * 8;
  int offA[4], offB[4];
#pragma unroll
  for (int i = 0; i < 4; ++i) {
    offA[i] = (wr * 64 + i * 16 + (l & 15)) * 32 + ps;
    offB[i] = (wc * 64 + i * 16 + (l & 15)) * 32 + ps;
  }

  f32x4 acc[4][4];
#pragma unroll
  for (int i = 0; i < 4; ++i)
#pragma unroll
    for (int j = 0; j < 4; ++j) acc[i][j] = (f32x4){0.f, 0.f, 0.f, 0.f};

  load_lds16(pA0ch, &ldsAh[0][0] + t0 * 8);
  load_lds16(pA1ch, &ldsAh[0][0] + t1 * 8);
  load_lds16(pA0cl, &ldsAl[0][0] + t0 * 8);
  load_lds16(pA1cl, &ldsAl[0][0] + t1 * 8);
  load_lds16(pB0h, &ldsBh[0][0] + t0 * 8);
  load_lds16(pB1h, &ldsBh[0][0] + t1 * 8);
  load_lds16(pB0l, &ldsBl[0][0] + t0 * 8);
  load_lds16(pB1l, &ldsBl[0][0] + t1 * 8);

  int buf = 0;
  for (int kt = 0; kt < KT; ++kt) {
    __syncthreads();
    if (kt + 1 < KT) {
      int k1 = kt + 1;
      const _Float16* a0 =
          (k1 < KC) ? pA0ch + k1 * 32 : pA0x + (k1 - KC) * 32;
      const _Float16* a1 =
          (k1 < KC) ? pA1ch + k1 * 32 : pA1x + (k1 - KC) * 32;
      load_lds16(a0, &ldsAh[buf ^ 1][0] + t0 * 8);
      load_lds16(a1, &ldsAh[buf ^ 1][0] + t1 * 8);
      if (k1 < KC) {
        load_lds16(pA0cl + k1 * 32, &ldsAl[buf ^ 1][0] + t0 * 8);
        load_lds16(pA1cl + k1 * 32, &ldsAl[buf ^ 1][0] + t1 * 8);
      }
      load_lds16(pB0h + k1 * 32, &ldsBh[buf ^ 1][0] + t0 * 8);
      load_lds16(pB1h + k1 * 32, &ldsBh[buf ^ 1][0] + t1 * 8);
      load_lds16(pB0l + k1 * 32, &ldsBl[buf ^ 1][0] + t0 * 8);
      load_lds16(pB1l + k1 * 32, &ldsBl[buf ^ 1][0] + t1 * 8);
    }
    f16x8 ah[4], bh[4], bl[4];
#pragma unroll
    for (int i = 0; i < 4; ++i) ah[i] = *(const f16x8*)(&ldsAh[buf][offA[i]]);
#pragma unroll
    for (int i = 0; i < 4; ++i) bh[i] = *(const f16x8*)(&ldsBh[buf][offB[i]]);
#pragma unroll
    for (int i = 0; i < 4; ++i) bl[i] = *(const f16x8*)(&ldsBl[buf][offB[i]]);
#pragma unroll
    for (int i = 0; i < 4; ++i)
#pragma unroll
      for (int j = 0; j < 4; ++j) {
        acc[i][j] = __builtin_amdgcn_mfma_f32_16x16x32_f16(ah[i], bh[j],
                                                           acc[i][j], 0, 0, 0);
        acc[i][j] = __builtin_amdgcn_mfma_f32_16x16x32_f16(ah[i], bl[j],
                                                           acc[i][j], 0, 0, 0);
      }
    if (kt < KC) {
      f16x8 al[4];
#pragma unroll
      for (int i = 0; i < 4; ++i)
        al[i] = *(const f16x8*)(&ldsAl[buf][offA[i]]);
#pragma unroll
      for (int i = 0; i < 4; ++i)
#pragma unroll
        for (int j = 0; j < 4; ++j)
          acc[i][j] = __builtin_amdgcn_mfma_f32_16x16x32_f16(al[i], bh[j],
                                                             acc[i][j], 0, 0, 0);
    }
    buf ^= 1;
  }

#pragma unroll
  for (int i = 0; i < 4; ++i) {
    int R = blk * 128 + wr * 64 + i * 16 + (l >> 4) * 4;
#pragma unroll
    for (int j = 0; j < 4; ++j) {
      int o = wc * 64 + j * 16 + (l & 15);
      float bv = bias[o];
#pragma unroll
      for (int rr = 0; rr < 4; ++rr) {
        int Rr = R + rr;
        int n = Rr >> 5, b = Rr & 31;
        size_t base = ((size_t)b * NN + n) * 64;
        float val = 1.f / (1.f + expf(-(acc[i][j][rr] + bv)));
        if (o < 64)
          RHX[base + o] = val * hx[base + o];
        else
          UBUF[base + (o - 64)] = val;
      }
    }
  }
}

// ---------------------------------------------------------------------------
// K6: candidate Wout GEMM via split-fp16 MFMA + fused tanh + gate -> out.
// ---------------------------------------------------------------------------
__global__ __launch_bounds__(256, 2) void k_wout_c_mfma(
    const _Float16* __restrict__ CAT2h, const _Float16* __restrict__ CAT2l,
    const _Float16* __restrict__ XP0, const _Float16* __restrict__ WTh,
    const _Float16* __restrict__ WTl, const float* __restrict__ bias,
    const float* __restrict__ UBUF, const float* __restrict__ hx,
    float* __restrict__ out) {
  constexpr int KTOT = 192, KC = 4, KT = 6;
  __shared__ _Float16 ldsAh[2][4096];
  __shared__ _Float16 ldsAl[2][4096];
  __shared__ _Float16 ldsBh[2][2048];
  __shared__ _Float16 ldsBl[2][2048];
  const int tid = threadIdx.x;
  const int blk = blockIdx.x;
  const int l = tid & 63;
  const int w = tid >> 6;

  const int t0 = tid, t1 = 256 + tid;
  const int r0 = t0 >> 2, q0 = (t0 & 3) ^ (r0 & 3);
  const int r1 = t1 >> 2, q1 = (t1 & 3) ^ (r1 & 3);
  const size_t R0 = (size_t)blk * 128 + r0, R1 = (size_t)blk * 128 + r1;
  const _Float16* pA0ch = CAT2h + R0 * 128 + q0 * 8;
  const _Float16* pA1ch = CAT2h + R1 * 128 + q1 * 8;
  const _Float16* pA0cl = CAT2l + R0 * 128 + q0 * 8;
  const _Float16* pA1cl = CAT2l + R1 * 128 + q1 * 8;
  const _Float16* pA0x = XP0 + R0 * 64 + q0 * 8;
  const _Float16* pA1x = XP0 + R1 * 64 + q1 * 8;
  const int rb = tid >> 2, qb = (tid & 3) ^ (rb & 3);
  const _Float16* pBh = WTh + (size_t)rb * KTOT + qb * 8;
  const _Float16* pBl = WTl + (size_t)rb * KTOT + qb * 8;

  const int ps = ((l >> 4) ^ (l & 3)) * 8;
  int offA[2], offB[4];
#pragma unroll
  for (int i = 0; i < 2; ++i)
    offA[i] = (w * 32 + i * 16 + (l & 15)) * 32 + ps;
#pragma unroll
  for (int j = 0; j < 4; ++j) offB[j] = (j * 16 + (l & 15)) * 32 + ps;

  f32x4 acc[2][4];
#pragma unroll
  for (int i = 0; i < 2; ++i)
#pragma unroll
    for (int j = 0; j < 4; ++j) acc[i][j] = (f32x4){0.f, 0.f, 0.f, 0.f};

  load_lds16(pA0ch, &ldsAh[0][0] + t0 * 8);
  load_lds16(pA1ch, &ldsAh[0][0] + t1 * 8);
  load_lds16(pA0cl, &ldsAl[0][0] + t0 * 8);
  load_lds16(pA1cl, &ldsAl[0][0] + t1 * 8);
  load_lds16(pBh, &ldsBh[0][0] + tid * 8);
  load_lds16(pBl, &ldsBl[0][0] + tid * 8);

  int buf = 0;
  for (int kt = 0; kt < KT; ++kt) {
    __syncthreads();
    if (kt + 1 < KT) {
      int k1 = kt + 1;
      const _Float16* a0 =
          (k1 < KC) ? pA0ch + k1 * 32 : pA0x + (k1 - KC) * 32;
      const _Float16* a1 =
          (k1 < KC) ? pA1ch + k1 * 32 : pA1x + (k1 - KC) * 32;
      load_lds16(a0, &ldsAh[buf ^ 1][0] + t0 * 8);
      load_lds16(a1, &ldsAh[buf ^ 1][0] + t1 * 8);
      if (k1 < KC) {
        load_lds16(pA0cl + k1 * 32, &ldsAl[buf ^ 1][0] + t0 * 8);
        load_lds16(pA1cl + k1 * 32, &ldsAl[buf ^ 1][0] + t1 * 8);
      }
      load_lds16(pBh + k1 * 32, &ldsBh[buf ^ 1][0] + tid * 8);
      load_lds16(pBl + k1 * 32, &ldsBl[buf ^ 1][0] + tid * 8);
    }
    f16x8 ah[2], bh[4], bl[4];
#pragma unroll
    for (int i = 0; i < 2; ++i) ah[i] = *(const f16x8*)(&ldsAh[buf][offA[i]]);
#pragma unroll
    for (int j = 0; j < 4; ++j) bh[j] = *(const f16x8*)(&ldsBh[buf][offB[j]]);
#pragma unroll
    for (int j = 0; j < 4; ++j) bl[j] = *(const f16x8*)(&ldsBl[buf][offB[j]]);
#pragma unroll
    for (int i = 0; i < 2; ++i)
#pragma unroll
      for (int j = 0; j < 4; ++j) {
        acc[i][j] = __builtin_amdgcn_mfma_f32_16x16x32_f16(ah[i], bh[j],
                                                           acc[i][j], 0, 0, 0);
        acc[i][j] = __builtin_amdgcn_mfma_f32_16x16x32_f16(ah[i], bl[j],
                                                           acc[i][j], 0, 0, 0);
      }
    if (kt < KC) {
      f16x8 al[2];
#pragma unroll
      for (int i = 0; i < 2; ++i)
        al[i] = *(const f16x8*)(&ldsAl[buf][offA[i]]);
#pragma unroll
      for (int i = 0; i < 2; ++i)
#pragma unroll
        for (int j = 0; j < 4; ++j)
          acc[i][j] = __builtin_amdgcn_mfma_f32_16x16x32_f16(al[i], bh[j],
                                                             acc[i][j], 0, 0, 0);
    }
    buf ^= 1;
  }

#pragma unroll
  for (int i = 0; i < 2; ++i) {
    int R = blk * 128 + w * 32 + i * 16 + (l >> 4) * 4;
#pragma unroll
    for (int j = 0; j < 4; ++j) {
      int o = j * 16 + (l & 15);
      float bv = bias[o];
#pragma unroll
      for (int rr = 0; rr < 4; ++rr) {
        int Rr = R + rr;
        int n = Rr >> 5, b = Rr & 31;
        size_t idx = ((size_t)b * NN + n) * 64 + o;
        float cval = tanhf(acc[i][j][rr] + bv);
        float u = UBUF[idx];
        out[idx] = u * hx[idx] + (1.f - u) * cval;
      }
    }
  }
}

// ---------------------------------------------------------------------------
extern "C" void kernel_launch(void* const* d_in, const int* in_sizes, int n_in,
                              void* d_out, int out_size, void* d_ws,
                              size_t ws_size, hipStream_t stream) {
  const float* inputs   = (const float*)d_in[0];
  const float* hx       = (const float*)d_in[1];
  const float* adj      = (const float*)d_in[2];
  const float* mask     = (const float*)d_in[3];
  const float* W_ru     = (const float*)d_in[4];
  const float* Watt_ru  = (const float*)d_in[5];
  const float* Watt1_ru = (const float*)d_in[6];
  const float* Wout_ru  = (const float*)d_in[7];
  const float* b_ru     = (const float*)d_in[8];
  const float* W_c      = (const float*)d_in[9];
  const float* Watt_c   = (const float*)d_in[10];
  const float* Watt1_c  = (const float*)d_in[11];
  const float* Wout_c   = (const float*)d_in[12];
  const float* b_c      = (const float*)d_in[13];

  // workspace arena (~178.5 MB):
  //   X0P   fp16 [32768][96]        @ 0           (6,291,456)
  //   XPD   fp16 [10][1024][CN]     @ 6,291,456   (83,886,080 max)
  //   XP0   fp16 [32768][O]         @ 90,177,536  (8,388,608 max)
  //   XP0T  fp16 [32*O][1024]       @ 98,566,144  (8,388,608 max)
  //   CAT2h fp16 [32768][2O]        @ 106,954,752 (16,777,216 max)
  //   CAT2l fp16 [32768][2O]        @ 123,731,968 (16,777,216 max)
  //   RHX   fp32                    @ 140,509,184 (8,388,608)
  //   UBUF  fp32                    @ 148,897,792 (8,388,608)
  //   A_all fp16 [10][1024][1024]   @ 157,286,400 (20,971,520)
  //   WThru/WTlru/WThc/WTlc         @ 178,257,920 .. 178,503,680
  char* ws = (char*)d_ws;
  _Float16*  X0P   = (_Float16*)(ws);
  _Float16*  XPD   = (_Float16*)(ws + 6291456);
  _Float16*  XP0   = (_Float16*)(ws + 90177536);
  _Float16*  XP0T  = (_Float16*)(ws + 98566144);
  _Float16*  CAT2h = (_Float16*)(ws + 106954752);
  _Float16*  CAT2l = (_Float16*)(ws + 123731968);
  float*     RHX   = (float*)(ws + 140509184);
  float*     UBUF  = (float*)(ws + 148897792);
  _Float16*  A_all = (_Float16*)(ws + 157286400);
  _Float16*  WThru = (_Float16*)(ws + 178257920);
  _Float16*  WTlru = (_Float16*)(ws + 178356224);
  _Float16*  WThc  = (_Float16*)(ws + 178454528);
  _Float16*  WTlc  = (_Float16*)(ws + 178479104);
  float*     out   = (float*)d_out;

  k_build_amats<<<1024, 256, 0, stream>>>(adj, mask, A_all);
  k_prep_wout<<<240, 256, 0, stream>>>(Wout_ru, Wout_c, WThru, WTlru, WThc,
                                       WTlc);

  // ---- gate gconv (O = 2U = 128) ----
  k_build_x0p<<<dim3(32, 16), 256, 0, stream>>>(inputs, hx, X0P);
  k_proj0_mfma<128><<<256, 256, 0, stream>>>(X0P, W_ru, XP0, XP0T);
  k_supports2_mfma<4096><<<dim3(32, 80), 256, 0, stream>>>(A_all, XP0T, XPD);
  k_attend_mfma<128><<<1024, 256, 0, stream>>>((const __half*)XPD, Watt_ru,
                                               Watt1_ru, CAT2h, CAT2l);
  k_wout_ru_mfma<<<256, 256, 0, stream>>>(CAT2h, CAT2l, XP0, WThru, WTlru,
                                          b_ru, hx, RHX, UBUF);
  // ---- candidate gconv (O = U = 64), state = r*hx ----
  k_build_x0p<<<dim3(32, 16), 256, 0, stream>>>(inputs, RHX, X0P);
  k_proj0_mfma<64><<<128, 256, 0, stream>>>(X0P, W_c, XP0, XP0T);
  k_supports2_mfma<2048><<<dim3(16, 80), 256, 0, stream>>>(A_all, XP0T, XPD);
  k_attend_mfma<64><<<1024, 256, 0, stream>>>((const __half*)XPD, Watt_c,
                                              Watt1_c, CAT2h, CAT2l);
  k_wout_c_mfma<<<256, 256, 0, stream>>>(CAT2h, CAT2l, XP0, WThc, WTlc, b_c,
                                         UBUF, hx, out);
}